// Round 8
// baseline (676.665 us; speedup 1.0000x reference)
//
#include <hip/hip_runtime.h>

#define TT 65
#define NSTEP 64

typedef __attribute__((ext_vector_type(8))) short bf16x8;
typedef __attribute__((ext_vector_type(4))) float f32x4;
typedef __attribute__((ext_vector_type(4))) unsigned int u32x4;
typedef __attribute__((ext_vector_type(2))) unsigned int u32x2;

__device__ constexpr float ATc[6][5] = {
    {0.f, 0.f, 0.f, 0.f, 0.f},
    {0.2f, 0.f, 0.f, 0.f, 0.f},
    {3.f/40.f, 9.f/40.f, 0.f, 0.f, 0.f},
    {44.f/45.f, -56.f/15.f, 32.f/9.f, 0.f, 0.f},
    {19372.f/6561.f, -25360.f/2187.f, 64448.f/6561.f, -212.f/729.f, 0.f},
    {9017.f/3168.f, -355.f/33.f, 46732.f/5247.f, 49.f/176.f, -5103.f/18656.f}
};
__device__ constexpr float BTc[6] = {35.f/384.f, 0.f, 500.f/1113.f, 125.f/192.f,
                                     -2187.f/6784.f, 11.f/84.f};

struct Frag3 { bf16x8 h, m, l; };

__device__ __forceinline__ float tanh_fast(float x) {
    float e = __expf(2.0f * x);
    return fmaf(-2.0f, __builtin_amdgcn_rcpf(e + 1.0f), 1.0f);
}

// 3-term bf16 truncation split: v = h + m + l + O(2^-24 |v|), exact residuals.
__device__ __forceinline__ Frag3 split8(const float* v) {
    unsigned int wh[4], wm[4], wl[4];
    #pragma unroll
    for (int p = 0; p < 4; ++p) {
        float a = v[2*p], b = v[2*p+1];
        unsigned int ua = __float_as_uint(a), ub = __float_as_uint(b);
        unsigned int uam = ua & 0xFFFF0000u, ubm = ub & 0xFFFF0000u;
        wh[p] = ubm | (ua >> 16);
        float ra = a - __uint_as_float(uam);
        float rb = b - __uint_as_float(ubm);
        unsigned int ura = __float_as_uint(ra), urb = __float_as_uint(rb);
        unsigned int uram = ura & 0xFFFF0000u, urbm = urb & 0xFFFF0000u;
        wm[p] = urbm | (ura >> 16);
        float sa = ra - __uint_as_float(uram);
        float sb = rb - __uint_as_float(urbm);
        wl[p] = (__float_as_uint(sb) & 0xFFFF0000u) | (__float_as_uint(sa) >> 16);
    }
    Frag3 f;
    u32x4 H = {wh[0], wh[1], wh[2], wh[3]};
    u32x4 M = {wm[0], wm[1], wm[2], wm[3]};
    u32x4 L = {wl[0], wl[1], wl[2], wl[3]};
    f.h = __builtin_bit_cast(bf16x8, H);
    f.m = __builtin_bit_cast(bf16x8, M);
    f.l = __builtin_bit_cast(bf16x8, L);
    return f;
}

// Split 2 scalars into 3 packed bf16-pair words (lo half = a, hi half = b).
__device__ __forceinline__ void split2pack(float a, float b,
                                           unsigned int& ph, unsigned int& pm,
                                           unsigned int& pl) {
    unsigned int ua = __float_as_uint(a), ub = __float_as_uint(b);
    unsigned int ham = ua & 0xFFFF0000u, hbm = ub & 0xFFFF0000u;
    ph = (ua >> 16) | hbm;
    float ra = a - __uint_as_float(ham);
    float rb = b - __uint_as_float(hbm);
    unsigned int ura = __float_as_uint(ra), urb = __float_as_uint(rb);
    unsigned int ram = ura & 0xFFFF0000u, rbm = urb & 0xFFFF0000u;
    pm = (ura >> 16) | rbm;
    float sa = ra - __uint_as_float(ram);
    float sb = rb - __uint_as_float(rbm);
    pl = (__float_as_uint(sa) >> 16) | (__float_as_uint(sb) & 0xFFFF0000u);
}

// 6-product split accumulate, 2 independent chains of 3.
__device__ __forceinline__ f32x4 mac3b(const Frag3& A, const Frag3& B, f32x4 cinit) {
    f32x4 a0 = cinit;
    f32x4 a1 = {0.f, 0.f, 0.f, 0.f};
    a0 = __builtin_amdgcn_mfma_f32_16x16x32_bf16(A.h, B.h, a0, 0, 0, 0);
    a1 = __builtin_amdgcn_mfma_f32_16x16x32_bf16(A.h, B.m, a1, 0, 0, 0);
    a0 = __builtin_amdgcn_mfma_f32_16x16x32_bf16(A.m, B.h, a0, 0, 0, 0);
    a1 = __builtin_amdgcn_mfma_f32_16x16x32_bf16(A.m, B.m, a1, 0, 0, 0);
    a0 = __builtin_amdgcn_mfma_f32_16x16x32_bf16(A.l, B.h, a0, 0, 0, 0);
    a1 = __builtin_amdgcn_mfma_f32_16x16x32_bf16(A.h, B.l, a1, 0, 0, 0);
    #pragma unroll
    for (int i = 0; i < 4; ++i) a0[i] += a1[i];
    return a0;
}

// Plane store P: u32 [pl 3][tile 18][r 16][p 8]. Tiles 0-7: z parity0,
// 8-15: z parity1, 16-17: yt halves. Word (tile,r,p) = bf16 pair (c=2p, 2p+1)
// of that tile's 16 channels, rows r. p XOR-swizzled by 4*((r>>2)&1):
// b64 writes and b128 reads both measure 2-way (free) bank aliasing.
#define PT(pl, tile) ((pl) * 2304 + (tile) * 128)

__device__ __forceinline__ Frag3 readPlanes(const unsigned int* P, int rbase, int tile) {
    Frag3 f;
    f.h = __builtin_bit_cast(bf16x8, *(const u32x4*)&P[PT(0, tile) + rbase]);
    f.m = __builtin_bit_cast(bf16x8, *(const u32x4*)&P[PT(1, tile) + rbase]);
    f.l = __builtin_bit_cast(bf16x8, *(const u32x4*)&P[PT(2, tile) + rbase]);
    return f;
}

__device__ __forceinline__ void publish2(unsigned int* P, int wbase, int tile0, int tile1,
                                         f32x4 v0, f32x4 v1) {
    unsigned int h0,m0,l0, h1,m1,l1, h2,m2,l2, h3,m3,l3;
    split2pack(v0[0], v0[1], h0, m0, l0);
    split2pack(v0[2], v0[3], h1, m1, l1);
    split2pack(v1[0], v1[1], h2, m2, l2);
    split2pack(v1[2], v1[3], h3, m3, l3);
    u32x2 a;
    a[0] = h0; a[1] = h1; *(u32x2*)&P[PT(0, tile0) + wbase] = a;
    a[0] = m0; a[1] = m1; *(u32x2*)&P[PT(1, tile0) + wbase] = a;
    a[0] = l0; a[1] = l1; *(u32x2*)&P[PT(2, tile0) + wbase] = a;
    a[0] = h2; a[1] = h3; *(u32x2*)&P[PT(0, tile1) + wbase] = a;
    a[0] = m2; a[1] = m3; *(u32x2*)&P[PT(1, tile1) + wbase] = a;
    a[0] = l2; a[1] = l3; *(u32x2*)&P[PT(2, tile1) + wbase] = a;
}

__device__ __forceinline__ f32x4 fma4s(float c, f32x4 a, f32x4 b) {  // b + c*a
    f32x4 r;
    #pragma unroll
    for (int i = 0; i < 4; ++i) r[i] = fmaf(c, a[i], b[i]);
    return r;
}

// Block = 4 waves = 16 rows, grid 512 (2 blocks/CU). Per stage, wave w:
//   m1 on its 2 c-tiles -> tanh -> publish z as bf16 h/m/l planes
//   -> ONE barrier -> read all z planes -> FULL m2 (K=128, redundant in all
//   waves) -> every wave holds complete k in D-layout -> redundant in-register
//   Butcher update (no reduction, no owner phase) -> publish yt planes
//   (identical values from every wave; self-read next stage, no barrier).
// z planes double-buffered by stage parity; yt overwrite fenced by z-barrier.
__global__ __launch_bounds__(256, 2)
void NeuralODE_dopri5_r8(const float* __restrict__ x, const float* __restrict__ tptr,
                         const float* __restrict__ W1, const float* __restrict__ b1,
                         const float* __restrict__ W2, const float* __restrict__ b2,
                         float* __restrict__ out)
{
    __shared__ unsigned int P[3 * 18 * 128];   // 27.6 KB

    const int tid = threadIdx.x;
    const int w   = tid >> 6;
    const int l   = tid & 63;
    const int r   = l & 15;
    const int q   = l >> 4;
    const int g4  = ((r >> 2) & 1) << 2;
    const int wbase = r * 8 + ((2 * q) ^ g4);            // b64 write base
    const int rbase = r * 8 + (((q & 1) << 2) ^ g4);     // b128 read base
    const int row = blockIdx.x * 16 + r;

    // ---- static weight fragments ----
    Frag3 W1f[2]; f32x4 b1f[2];
    {
        float v[8];
        #pragma unroll
        for (int i = 0; i < 2; ++i) {
            int m = 2 * w + i;
            *(f32x4*)&v[0] = *(const f32x4*)&W1[(16*m + r) * 32 + 8*q];
            *(f32x4*)&v[4] = *(const f32x4*)&W1[(16*m + r) * 32 + 8*q + 4];
            W1f[i] = split8(v);
            b1f[i] = *(const f32x4*)&b1[16*m + 4*q];
        }
    }
    Frag3 W2f[2][4]; f32x4 b2f[2];
    {
        float v[8];
        #pragma unroll
        for (int dt = 0; dt < 2; ++dt) {
            b2f[dt] = *(const f32x4*)&b2[16*dt + 4*q];
            #pragma unroll
            for (int tt = 0; tt < 4; ++tt) {
                *(f32x4*)&v[0] = *(const f32x4*)&W2[(16*dt + r) * 128 + 32*tt + 8*q];
                *(f32x4*)&v[4] = *(const f32x4*)&W2[(16*dt + r) * 128 + 32*tt + 8*q + 4];
                W2f[dt][tt] = split8(v);
            }
        }
    }

    const float h_all = tptr[l + 1] - tptr[l];   // t row 0 (uniform); lane s holds h_s

    // ---- state (full per-lane slice, redundant across waves) ----
    f32x4 y[2];
    y[0] = *(const f32x4*)&x[(size_t)row * (TT*32) + 4*q];
    y[1] = *(const f32x4*)&x[(size_t)row * (TT*32) + 16 + 4*q];
    if (w == 0) {
        *(f32x4*)&out[(size_t)row * (TT*32) + 4*q]      = y[0];
        *(f32x4*)&out[(size_t)row * (TT*32) + 16 + 4*q] = y[1];
    }
    f32x4 kk[5][2];

    publish2(P, wbase, 16, 17, y[0], y[1]);      // initial yt (self-read; no barrier)

    #pragma unroll 1
    for (int step = 0; step < NSTEP; ++step) {
        const float h = __shfl(h_all, step);
        f32x4 bacc[2] = {{0,0,0,0},{0,0,0,0}};

        #pragma unroll
        for (int s = 0; s < 6; ++s) {
            const int zb = (s & 1) * 8;

            // ---- B1 from yt planes; m1 on own 2 c-tiles; tanh ----
            Frag3 B1 = readPlanes(P, rbase, 16 + (q >> 1));
            f32x4 z0 = mac3b(W1f[0], B1, b1f[0]);
            f32x4 z1 = mac3b(W1f[1], B1, b1f[1]);
            #pragma unroll
            for (int e = 0; e < 4; ++e) { z0[e] = tanh_fast(z0[e]); z1[e] = tanh_fast(z1[e]); }

            publish2(P, wbase, zb + 2*w, zb + 2*w + 1, z0, z1);
            __syncthreads();                     // the only barrier per stage

            // ---- full m2: K=128, 4 independent MFMA chains ----
            f32x4 a0 = b2f[0], a1 = {0,0,0,0};
            f32x4 a2 = b2f[1], a3 = {0,0,0,0};
            #pragma unroll
            for (int tt = 0; tt < 4; ++tt) {
                Frag3 B2 = readPlanes(P, rbase, zb + 2*tt + (q >> 1));
                a0 = __builtin_amdgcn_mfma_f32_16x16x32_bf16(W2f[0][tt].h, B2.h, a0, 0, 0, 0);
                a1 = __builtin_amdgcn_mfma_f32_16x16x32_bf16(W2f[0][tt].h, B2.m, a1, 0, 0, 0);
                a2 = __builtin_amdgcn_mfma_f32_16x16x32_bf16(W2f[1][tt].h, B2.h, a2, 0, 0, 0);
                a3 = __builtin_amdgcn_mfma_f32_16x16x32_bf16(W2f[1][tt].h, B2.m, a3, 0, 0, 0);
                a0 = __builtin_amdgcn_mfma_f32_16x16x32_bf16(W2f[0][tt].m, B2.h, a0, 0, 0, 0);
                a1 = __builtin_amdgcn_mfma_f32_16x16x32_bf16(W2f[0][tt].m, B2.m, a1, 0, 0, 0);
                a2 = __builtin_amdgcn_mfma_f32_16x16x32_bf16(W2f[1][tt].m, B2.h, a2, 0, 0, 0);
                a3 = __builtin_amdgcn_mfma_f32_16x16x32_bf16(W2f[1][tt].m, B2.m, a3, 0, 0, 0);
                a0 = __builtin_amdgcn_mfma_f32_16x16x32_bf16(W2f[0][tt].l, B2.h, a0, 0, 0, 0);
                a1 = __builtin_amdgcn_mfma_f32_16x16x32_bf16(W2f[0][tt].h, B2.l, a1, 0, 0, 0);
                a2 = __builtin_amdgcn_mfma_f32_16x16x32_bf16(W2f[1][tt].l, B2.h, a2, 0, 0, 0);
                a3 = __builtin_amdgcn_mfma_f32_16x16x32_bf16(W2f[1][tt].h, B2.l, a3, 0, 0, 0);
            }
            f32x4 k0, k1;
            #pragma unroll
            for (int e = 0; e < 4; ++e) { k0[e] = a0[e] + a1[e]; k1[e] = a2[e] + a3[e]; }

            // ---- redundant Butcher update (all waves identical) ----
            bacc[0] = fma4s(BTc[s], k0, bacc[0]);
            bacc[1] = fma4s(BTc[s], k1, bacc[1]);
            if (s < 5) { kk[s][0] = k0; kk[s][1] = k1; }

            f32x4 yt0, yt1;
            if (s < 5) {
                f32x4 ax = {0,0,0,0}, ay = {0,0,0,0};
                #pragma unroll
                for (int j = 0; j < 5; ++j)
                    if (j < s) { ax = fma4s(ATc[s+1][j], kk[j][0], ax);
                                 ay = fma4s(ATc[s+1][j], kk[j][1], ay); }
                ax = fma4s(ATc[s+1][s], k0, ax);
                ay = fma4s(ATc[s+1][s], k1, ay);
                yt0 = fma4s(h, ax, y[0]);
                yt1 = fma4s(h, ay, y[1]);
            } else {
                y[0] = fma4s(h, bacc[0], y[0]);
                y[1] = fma4s(h, bacc[1], y[1]);
                yt0 = y[0]; yt1 = y[1];
                if (w == 0) {
                    size_t o = (size_t)row * (TT*32) + (size_t)(step + 1) * 32;
                    *(f32x4*)&out[o + 4*q]      = y[0];
                    *(f32x4*)&out[o + 16 + 4*q] = y[1];
                }
            }
            publish2(P, wbase, 16, 17, yt0, yt1);   // identical from every wave
            // no second barrier: next overwrite of these slots is fenced by
            // the z-barrier of the NEXT stage (see header comment)
        }
    }
}

extern "C" void kernel_launch(void* const* d_in, const int* in_sizes, int n_in,
                              void* d_out, int out_size, void* d_ws, size_t ws_size,
                              hipStream_t stream) {
    (void)in_sizes; (void)n_in; (void)d_ws; (void)ws_size; (void)out_size;
    const float* x  = (const float*)d_in[0];
    const float* t  = (const float*)d_in[1];
    // d_in[2] = itv, d_in[3] = itv_mask : unused by the reference math
    const float* W1 = (const float*)d_in[4];
    const float* b1 = (const float*)d_in[5];
    const float* W2 = (const float*)d_in[6];
    const float* b2 = (const float*)d_in[7];
    float* out = (float*)d_out;

    dim3 grid(8192 / 16);   // 512 blocks x 4 waves (2 blocks/CU)
    dim3 block(256);
    hipLaunchKernelGGL(NeuralODE_dopri5_r8, grid, block, 0, stream,
                       x, t, W1, b1, W2, b2, out);
}

// Round 9
// 468.278 us; speedup vs baseline: 1.4450x; 1.4450x over previous
//
#include <hip/hip_runtime.h>

#define TT 65
#define NSTEP 64

typedef __attribute__((ext_vector_type(8))) short bf16x8;
typedef __attribute__((ext_vector_type(4))) short bf16x4;
typedef __attribute__((ext_vector_type(4))) float f32x4;
typedef __attribute__((ext_vector_type(4))) unsigned int u32x4;
typedef __attribute__((ext_vector_type(2))) unsigned int u32x2;

// 16x16x16 bf16 MFMA builtin (name varies across ROCm versions) — R5-verified
#if __has_builtin(__builtin_amdgcn_mfma_f32_16x16x16bf16_1k)
#define MFMA16(A,B,C) __builtin_amdgcn_mfma_f32_16x16x16bf16_1k((A),(B),(C),0,0,0)
#elif __has_builtin(__builtin_amdgcn_mfma_f32_16x16x16_bf16)
#define MFMA16(A,B,C) __builtin_amdgcn_mfma_f32_16x16x16_bf16((A),(B),(C),0,0,0)
#else
static __device__ __forceinline__ f32x4 mfma16_asm(bf16x4 a, bf16x4 b, f32x4 c) {
    f32x4 d;
    asm("v_mfma_f32_16x16x16_bf16 %0, %1, %2, %3" : "=v"(d) : "v"(a), "v"(b), "v"(c));
    return d;
}
#define MFMA16(A,B,C) mfma16_asm((A),(B),(C))
#endif

__device__ constexpr float ATc[6][5] = {
    {0.f, 0.f, 0.f, 0.f, 0.f},
    {0.2f, 0.f, 0.f, 0.f, 0.f},
    {3.f/40.f, 9.f/40.f, 0.f, 0.f, 0.f},
    {44.f/45.f, -56.f/15.f, 32.f/9.f, 0.f, 0.f},
    {19372.f/6561.f, -25360.f/2187.f, 64448.f/6561.f, -212.f/729.f, 0.f},
    {9017.f/3168.f, -355.f/33.f, 46732.f/5247.f, 49.f/176.f, -5103.f/18656.f}
};
__device__ constexpr float BTc[6] = {35.f/384.f, 0.f, 500.f/1113.f, 125.f/192.f,
                                     -2187.f/6784.f, 11.f/84.f};

struct Frag3  { bf16x8 h, m, l; };
struct Frag3s { bf16x4 h, m, l; };

__device__ __forceinline__ float tanh_fast(float x) {
    float e = __expf(2.0f * x);
    return fmaf(-2.0f, __builtin_amdgcn_rcpf(e + 1.0f), 1.0f);
}

// 3-term bf16 truncation splits (exact residual bit-slices, error ~2^-24)
__device__ __forceinline__ Frag3 split8(const float* v) {
    unsigned int wh[4], wm[4], wl[4];
    #pragma unroll
    for (int p = 0; p < 4; ++p) {
        float a = v[2*p], b = v[2*p+1];
        unsigned int ua = __float_as_uint(a), ub = __float_as_uint(b);
        unsigned int uam = ua & 0xFFFF0000u, ubm = ub & 0xFFFF0000u;
        wh[p] = ubm | (ua >> 16);
        float ra = a - __uint_as_float(uam);
        float rb = b - __uint_as_float(ubm);
        unsigned int ura = __float_as_uint(ra), urb = __float_as_uint(rb);
        unsigned int uram = ura & 0xFFFF0000u, urbm = urb & 0xFFFF0000u;
        wm[p] = urbm | (ura >> 16);
        float sa = ra - __uint_as_float(uram);
        float sb = rb - __uint_as_float(urbm);
        wl[p] = (__float_as_uint(sb) & 0xFFFF0000u) | (__float_as_uint(sa) >> 16);
    }
    Frag3 f;
    u32x4 H = {wh[0], wh[1], wh[2], wh[3]};
    u32x4 M = {wm[0], wm[1], wm[2], wm[3]};
    u32x4 L = {wl[0], wl[1], wl[2], wl[3]};
    f.h = __builtin_bit_cast(bf16x8, H);
    f.m = __builtin_bit_cast(bf16x8, M);
    f.l = __builtin_bit_cast(bf16x8, L);
    return f;
}

__device__ __forceinline__ Frag3s split4(f32x4 v) {
    unsigned int wh[2], wm[2], wl[2];
    #pragma unroll
    for (int p = 0; p < 2; ++p) {
        float a = v[2*p], b = v[2*p+1];
        unsigned int ua = __float_as_uint(a), ub = __float_as_uint(b);
        unsigned int uam = ua & 0xFFFF0000u, ubm = ub & 0xFFFF0000u;
        wh[p] = ubm | (ua >> 16);
        float ra = a - __uint_as_float(uam);
        float rb = b - __uint_as_float(ubm);
        unsigned int ura = __float_as_uint(ra), urb = __float_as_uint(rb);
        unsigned int uram = ura & 0xFFFF0000u, urbm = urb & 0xFFFF0000u;
        wm[p] = urbm | (ura >> 16);
        float sa = ra - __uint_as_float(uram);
        float sb = rb - __uint_as_float(urbm);
        wl[p] = (__float_as_uint(sa) >> 16) | (__float_as_uint(sb) & 0xFFFF0000u);
    }
    Frag3s f;
    u32x2 H = {wh[0], wh[1]};
    u32x2 M = {wm[0], wm[1]};
    u32x2 L = {wl[0], wl[1]};
    f.h = __builtin_bit_cast(bf16x4, H);
    f.m = __builtin_bit_cast(bf16x4, M);
    f.l = __builtin_bit_cast(bf16x4, L);
    return f;
}

// single-scalar 3-term split (owner publish)
__device__ __forceinline__ void split1(float a, unsigned short& h,
                                       unsigned short& m, unsigned short& l) {
    unsigned int ua = __float_as_uint(a);
    h = (unsigned short)(ua >> 16);
    float r1 = a - __uint_as_float(ua & 0xFFFF0000u);
    unsigned int u1 = __float_as_uint(r1);
    m = (unsigned short)(u1 >> 16);
    float r2 = r1 - __uint_as_float(u1 & 0xFFFF0000u);
    l = (unsigned short)(__float_as_uint(r2) >> 16);
}

// 6-product split accumulates, 2 independent chains of 3
__device__ __forceinline__ f32x4 mac3b(const Frag3& A, const Frag3& B, f32x4 cinit) {
    f32x4 a0 = cinit;
    f32x4 a1 = {0.f, 0.f, 0.f, 0.f};
    a0 = __builtin_amdgcn_mfma_f32_16x16x32_bf16(A.h, B.h, a0, 0, 0, 0);
    a1 = __builtin_amdgcn_mfma_f32_16x16x32_bf16(A.h, B.m, a1, 0, 0, 0);
    a0 = __builtin_amdgcn_mfma_f32_16x16x32_bf16(A.m, B.h, a0, 0, 0, 0);
    a1 = __builtin_amdgcn_mfma_f32_16x16x32_bf16(A.m, B.m, a1, 0, 0, 0);
    a0 = __builtin_amdgcn_mfma_f32_16x16x32_bf16(A.l, B.h, a0, 0, 0, 0);
    a1 = __builtin_amdgcn_mfma_f32_16x16x32_bf16(A.h, B.l, a1, 0, 0, 0);
    #pragma unroll
    for (int i = 0; i < 4; ++i) a0[i] += a1[i];
    return a0;
}
__device__ __forceinline__ f32x4 mac3s(const Frag3s& A, const Frag3s& B) {
    f32x4 a0 = {0.f, 0.f, 0.f, 0.f};
    f32x4 a1 = {0.f, 0.f, 0.f, 0.f};
    a0 = MFMA16(A.h, B.h, a0);
    a1 = MFMA16(A.h, B.m, a1);
    a0 = MFMA16(A.m, B.h, a0);
    a1 = MFMA16(A.m, B.m, a1);
    a0 = MFMA16(A.l, B.h, a0);
    a1 = MFMA16(A.h, B.l, a1);
    #pragma unroll
    for (int i = 0; i < 4; ++i) a0[i] += a1[i];
    return a0;
}

// yt planes: u32 [pl 3][tile 2][r 16][12] (row stride 12 u32 for bank spread;
// words 0-7 used). Word (tile,r,p) = bf16 pair (d = 2p, 2p+1) of that tile,
// XOR-swizzled p^g4, g4 = ((r>>2)&1)<<2 (4-word blocks preserved for b128).
#define PT32(pl, tt) ((pl) * 384 + (tt) * 192)

// Block = 8 waves = 512 thr = 16 rows. Per stage, wave w:
//   read B1 from yt planes (MFMA-ready, no split) -> m1 tile w (6 MFMA-32)
//   -> tanh x4 -> split4 -> m2 via 16x16x16 with z IN REGISTERS (D-frag ==
//   B-frag layout identity, R5-verified): 2 d-tiles x 6 MFMA-16 over own K=16
//   -> partials to pb -> barrier -> owner (lane owns (d=4w+q, r)): reduce 8
//   partials, Butcher update, publish next yt planes (3 x ds_write_b16)
//   -> barrier. z never touches LDS; yt split exactly once per value.
__global__ __launch_bounds__(512, 4)
void NeuralODE_dopri5_r9(const float* __restrict__ x, const float* __restrict__ tptr,
                         const float* __restrict__ W1, const float* __restrict__ b1,
                         const float* __restrict__ W2, const float* __restrict__ b2,
                         float* __restrict__ out)
{
    __shared__ unsigned int ytp[3 * 2 * 192];        // 4.6 KB yt planes
    __shared__ __align__(16) float pb[8 * 520];      // 16.6 KB partials (stride 520)

    const int tid = threadIdx.x;
    const int w   = tid >> 6;
    const int l   = tid & 63;
    const int r   = l & 15;
    const int q   = l >> 4;
    const int g4  = ((r >> 2) & 1) << 2;
    const int swz = (r & 7) << 2;
    const int row = blockIdx.x * 16 + r;
    const int d_own = 4 * w + q;                     // owned (d, r) state scalar

    // ---- static weight fragments ----
    Frag3 W1f; f32x4 b1f;
    {
        float v[8];
        *(f32x4*)&v[0] = *(const f32x4*)&W1[(16*w + r) * 32 + 8*q];
        *(f32x4*)&v[4] = *(const f32x4*)&W1[(16*w + r) * 32 + 8*q + 4];
        W1f = split8(v);
        b1f = *(const f32x4*)&b1[16*w + 4*q];
    }
    Frag3s W2f[2];
    #pragma unroll
    for (int dt = 0; dt < 2; ++dt) {
        f32x4 v = *(const f32x4*)&W2[(16*dt + r) * 128 + 16*w + 4*q];
        W2f[dt] = split4(v);
    }
    const float b2e = b2[d_own];

    // ---- loop-invariant LDS addressing ----
    const int b1base = r * 12 + (((q & 1) << 2) ^ g4);
    const int b1tile = (q >> 1) * 192;
    unsigned short* const Y16 = (unsigned short*)ytp;
    const int wp   = (2 * (w & 3) + (q >> 1)) ^ g4;
    const int yt_s = ((w >> 2) * 192 + r * 12 + wp) * 2 + (q & 1);  // + pl*768
    float* const pw0 = &pb[w * 520 + r * 32 + (( 0 + 4*q) ^ swz)];
    float* const pw1 = &pb[w * 520 + r * 32 + ((16 + 4*q) ^ swz)];
    const float* const prd = &pb[r * 32 + (d_own ^ swz)];            // + v*520

    const float h_all = tptr[l + 1] - tptr[l];   // t row 0 uniform; lane s has h_s

    // ---- state init: owner scalar y, publish planes, emit step 0 ----
    float y = x[(size_t)row * (TT*32) + d_own];
    out[(size_t)row * (TT*32) + d_own] = y;
    {
        unsigned short sh, sm, sl;
        split1(y, sh, sm, sl);
        Y16[yt_s] = sh; Y16[768 + yt_s] = sm; Y16[1536 + yt_s] = sl;
    }
    float kx[5];
    #pragma unroll
    for (int j = 0; j < 5; ++j) kx[j] = 0.f;
    __syncthreads();

    #pragma unroll 1
    for (int step = 0; step < NSTEP; ++step) {
        const float h = __shfl(h_all, step);
        float bacc = 0.f;

        #pragma unroll
        for (int s = 0; s < 6; ++s) {
            // ---- B1 from planes (ready-to-MFMA) ----
            Frag3 B1;
            B1.h = __builtin_bit_cast(bf16x8, *(const u32x4*)&ytp[PT32(0,0) + b1tile + b1base]);
            B1.m = __builtin_bit_cast(bf16x8, *(const u32x4*)&ytp[PT32(1,0) + b1tile + b1base]);
            B1.l = __builtin_bit_cast(bf16x8, *(const u32x4*)&ytp[PT32(2,0) + b1tile + b1base]);

            // ---- m1 tile w + tanh + split (z stays in registers) ----
            f32x4 z = mac3b(W1f, B1, b1f);
            #pragma unroll
            for (int e = 0; e < 4; ++e) z[e] = tanh_fast(z[e]);
            Frag3s Z = split4(z);

            // ---- m2: 2 d-tiles over own K=16 slice (layout identity) ----
            f32x4 p0 = mac3s(W2f[0], Z);
            f32x4 p1 = mac3s(W2f[1], Z);
            *(f32x4*)pw0 = p0;
            *(f32x4*)pw1 = p1;
            __syncthreads();

            // ---- owner: reduce 8 partials for (d_own, r) ----
            float pv[8];
            #pragma unroll
            for (int v8 = 0; v8 < 8; ++v8) pv[v8] = prd[v8 * 520];
            float kd = b2e + (((pv[0] + pv[1]) + (pv[2] + pv[3]))
                            + ((pv[4] + pv[5]) + (pv[6] + pv[7])));
            if (s < 5) kx[s] = kd;
            bacc = fmaf(BTc[s], kd, bacc);

            float yt;
            if (s < 5) {
                float at = ATc[s+1][s] * kd;
                #pragma unroll
                for (int j = 0; j < 5; ++j)
                    if (j < s) at = fmaf(ATc[s+1][j], kx[j], at);
                yt = fmaf(h, at, y);
            } else {
                y = fmaf(h, bacc, y);
                yt = y;
                out[(size_t)row * (TT*32) + (size_t)(step+1) * 32 + d_own] = y;
            }
            unsigned short sh, sm, sl;
            split1(yt, sh, sm, sl);
            Y16[yt_s] = sh; Y16[768 + yt_s] = sm; Y16[1536 + yt_s] = sl;
            __syncthreads();
        }
    }
}

extern "C" void kernel_launch(void* const* d_in, const int* in_sizes, int n_in,
                              void* d_out, int out_size, void* d_ws, size_t ws_size,
                              hipStream_t stream) {
    (void)in_sizes; (void)n_in; (void)d_ws; (void)ws_size; (void)out_size;
    const float* x  = (const float*)d_in[0];
    const float* t  = (const float*)d_in[1];
    // d_in[2] = itv, d_in[3] = itv_mask : unused by the reference math
    const float* W1 = (const float*)d_in[4];
    const float* b1 = (const float*)d_in[5];
    const float* W2 = (const float*)d_in[6];
    const float* b2 = (const float*)d_in[7];
    float* out = (float*)d_out;

    dim3 grid(8192 / 16);   // 512 blocks x 8 waves = 4096 waves (16/CU, 4/SIMD)
    dim3 block(512);
    hipLaunchKernelGGL(NeuralODE_dopri5_r9, grid, block, 0, stream,
                       x, t, W1, b1, W2, b2, out);
}

// Round 10
// 349.486 us; speedup vs baseline: 1.9362x; 1.3399x over previous
//
#include <hip/hip_runtime.h>

#define TT 65
#define NSTEP 64

typedef __attribute__((ext_vector_type(8))) short bf16x8;
typedef __attribute__((ext_vector_type(4))) short bf16x4;
typedef __attribute__((ext_vector_type(4))) float f32x4;
typedef __attribute__((ext_vector_type(4))) unsigned int u32x4;
typedef __attribute__((ext_vector_type(2))) unsigned int u32x2;

// 16x16x16 bf16 MFMA builtin (name varies across ROCm versions) — R5/R9-verified
#if __has_builtin(__builtin_amdgcn_mfma_f32_16x16x16bf16_1k)
#define MFMA16(A,B,C) __builtin_amdgcn_mfma_f32_16x16x16bf16_1k((A),(B),(C),0,0,0)
#elif __has_builtin(__builtin_amdgcn_mfma_f32_16x16x16_bf16)
#define MFMA16(A,B,C) __builtin_amdgcn_mfma_f32_16x16x16_bf16((A),(B),(C),0,0,0)
#else
static __device__ __forceinline__ f32x4 mfma16_asm(bf16x4 a, bf16x4 b, f32x4 c) {
    f32x4 d;
    asm("v_mfma_f32_16x16x16_bf16 %0, %1, %2, %3" : "=v"(d) : "v"(a), "v"(b), "v"(c));
    return d;
}
#define MFMA16(A,B,C) mfma16_asm((A),(B),(C))
#endif

__device__ constexpr float ATc[6][5] = {
    {0.f, 0.f, 0.f, 0.f, 0.f},
    {0.2f, 0.f, 0.f, 0.f, 0.f},
    {3.f/40.f, 9.f/40.f, 0.f, 0.f, 0.f},
    {44.f/45.f, -56.f/15.f, 32.f/9.f, 0.f, 0.f},
    {19372.f/6561.f, -25360.f/2187.f, 64448.f/6561.f, -212.f/729.f, 0.f},
    {9017.f/3168.f, -355.f/33.f, 46732.f/5247.f, 49.f/176.f, -5103.f/18656.f}
};
__device__ constexpr float BTc[6] = {35.f/384.f, 0.f, 500.f/1113.f, 125.f/192.f,
                                     -2187.f/6784.f, 11.f/84.f};

struct Frag2  { bf16x8 h, m; };
struct Frag2s { bf16x4 h, m; };

__device__ __forceinline__ float tanh_fast(float x) {
    float e = __expf(2.0f * x);
    return fmaf(-2.0f, __builtin_amdgcn_rcpf(e + 1.0f), 1.0f);
}

// 2-term split: v = h + m + O(2^-17 |v|). h = truncation (residual exact);
// m = round-nearest of residual (the +0x8000 carry trick).
__device__ __forceinline__ Frag2 split8_2(const float* v) {
    unsigned int wh[4], wm[4];
    #pragma unroll
    for (int p = 0; p < 4; ++p) {
        float a = v[2*p], b = v[2*p+1];
        unsigned int ua = __float_as_uint(a), ub = __float_as_uint(b);
        unsigned int uam = ua & 0xFFFF0000u, ubm = ub & 0xFFFF0000u;
        wh[p] = ubm | (ua >> 16);
        float ra = a - __uint_as_float(uam);
        float rb = b - __uint_as_float(ubm);
        wm[p] = ((__float_as_uint(rb) + 0x8000u) & 0xFFFF0000u)
              | ((__float_as_uint(ra) + 0x8000u) >> 16);
    }
    Frag2 f;
    u32x4 H = {wh[0], wh[1], wh[2], wh[3]};
    u32x4 M = {wm[0], wm[1], wm[2], wm[3]};
    f.h = __builtin_bit_cast(bf16x8, H);
    f.m = __builtin_bit_cast(bf16x8, M);
    return f;
}

__device__ __forceinline__ Frag2s split4_2(f32x4 v) {
    unsigned int wh[2], wm[2];
    #pragma unroll
    for (int p = 0; p < 2; ++p) {
        float a = v[2*p], b = v[2*p+1];
        unsigned int ua = __float_as_uint(a), ub = __float_as_uint(b);
        unsigned int uam = ua & 0xFFFF0000u, ubm = ub & 0xFFFF0000u;
        wh[p] = ubm | (ua >> 16);
        float ra = a - __uint_as_float(uam);
        float rb = b - __uint_as_float(ubm);
        wm[p] = ((__float_as_uint(rb) + 0x8000u) & 0xFFFF0000u)
              | ((__float_as_uint(ra) + 0x8000u) >> 16);
    }
    Frag2s f;
    u32x2 H = {wh[0], wh[1]};
    u32x2 M = {wm[0], wm[1]};
    f.h = __builtin_bit_cast(bf16x4, H);
    f.m = __builtin_bit_cast(bf16x4, M);
    return f;
}

// Split 2 scalars into 2 packed bf16-pair words (lo half = a, hi half = b).
__device__ __forceinline__ void split2pack_2(float a, float b,
                                             unsigned int& ph, unsigned int& pm) {
    unsigned int ua = __float_as_uint(a), ub = __float_as_uint(b);
    unsigned int ham = ua & 0xFFFF0000u, hbm = ub & 0xFFFF0000u;
    ph = (ua >> 16) | hbm;
    float ra = a - __uint_as_float(ham);
    float rb = b - __uint_as_float(hbm);
    pm = ((__float_as_uint(ra) + 0x8000u) >> 16)
       | ((__float_as_uint(rb) + 0x8000u) & 0xFFFF0000u);
}

// 3-product split accumulate: (Ah+Am)(Bh+Bm) minus the Mm term; err ~2^-15.5.
__device__ __forceinline__ f32x4 mac2b(const Frag2& A, const Frag2& B, f32x4 cinit) {
    f32x4 a0 = cinit;
    f32x4 a1 = {0.f, 0.f, 0.f, 0.f};
    a0 = __builtin_amdgcn_mfma_f32_16x16x32_bf16(A.h, B.h, a0, 0, 0, 0);
    a1 = __builtin_amdgcn_mfma_f32_16x16x32_bf16(A.h, B.m, a1, 0, 0, 0);
    a0 = __builtin_amdgcn_mfma_f32_16x16x32_bf16(A.m, B.h, a0, 0, 0, 0);
    #pragma unroll
    for (int i = 0; i < 4; ++i) a0[i] += a1[i];
    return a0;
}

// Block = 4 waves = 16 rows, grid 512 (2 blocks/CU) — R6 geometry (the proven
// optimum: two independent blocks per CU self-overlap across barriers).
// Per stage, wave w:
//   B1 from yt bf16 planes (split once by owner; MFMA-ready) -> m1 on its 2
//   c-tiles (3-product, 6 MFMA-32) -> tanh -> split4_2 -> m2 IN REGISTERS via
//   the 16x16x16 D-frag==B-frag identity (R5/R9-verified): own K=32 slice =
//   own 2 z tiles, 2 d-tiles x 3 products x 2 K-slices = 12 MFMA-16 ->
//   partials -> barrier -> owner (lane owns d0=8w+2q pair): reduce 4 partials,
//   Butcher update, publish 2 yt planes -> barrier. z never touches LDS.
__global__ __launch_bounds__(256, 2)
void NeuralODE_dopri5_r10(const float* __restrict__ x, const float* __restrict__ tptr,
                          const float* __restrict__ W1, const float* __restrict__ b1,
                          const float* __restrict__ W2, const float* __restrict__ b2,
                          float* __restrict__ out)
{
    __shared__ unsigned int ytp[2][16][16];          // yt planes h/m: 2 KB
    __shared__ __align__(16) float pb[4][512];       // m2 partials: 8 KB

    const int tid = threadIdx.x;
    const int w   = tid >> 6;
    const int l   = tid & 63;
    const int r   = l & 15;
    const int q   = l >> 4;
    const int g   = (r >> 1) & 3;                    // plane block swizzle (R6-proven)
    const int swz = (r & 7) << 2;                    // f32-block swizzle (R4-proven)
    const int row = blockIdx.x * 16 + r;
    const int d0  = 8 * w + 2 * q;                   // owned state pair

    // ---- static weight fragments ----
    Frag2 W1f[2];
    f32x4 b1f[2];
    {
        float v[8];
        #pragma unroll
        for (int i = 0; i < 2; ++i) {
            int m = 2 * w + i;
            *(f32x4*)&v[0] = *(const f32x4*)&W1[(16*m + r) * 32 + 8*q];
            *(f32x4*)&v[4] = *(const f32x4*)&W1[(16*m + r) * 32 + 8*q + 4];
            W1f[i] = split8_2(v);
            b1f[i] = *(const f32x4*)&b1[16*m + 4*q];
        }
    }
    // W2 fragments for MFMA-16: A[r][4q+j] = W2[16dt + r][32w + 16ks + 4q + j]
    Frag2s W2f[2][2];
    #pragma unroll
    for (int dt = 0; dt < 2; ++dt)
        #pragma unroll
        for (int ks = 0; ks < 2; ++ks) {
            f32x4 v = *(const f32x4*)&W2[(16*dt + r) * 128 + 32*w + 16*ks + 4*q];
            W2f[dt][ks] = split4_2(v);
        }
    const float b2x = b2[d0], b2y = b2[d0 + 1];

    // ---- loop-invariant LDS addresses ----
    unsigned int* const ytw0 = &ytp[0][r][((w ^ g) << 2) + q];
    unsigned int* const ytw1 = &ytp[1][r][((w ^ g) << 2) + q];
    const u32x4* const ytr0 = (const u32x4*)&ytp[0][r][(q ^ g) << 2];
    const u32x4* const ytr1 = (const u32x4*)&ytp[1][r][(q ^ g) << 2];
    float* const pbw0 = &pb[w][r * 32 + ((     4*q) ^ swz)];
    float* const pbw1 = &pb[w][r * 32 + ((16 + 4*q) ^ swz)];
    const float* const pred = &pb[0][r * 32 + (d0 ^ swz)];   // + 512*v

    const float h_all = tptr[l + 1] - tptr[l];   // t row 0 uniform; lane s has h_s

    // ---- state init ----
    float2 y0 = *(const float2*)&x[(size_t)row * (TT*32) + d0];
    float yx = y0.x, yy = y0.y;
    {
        unsigned int ph, pm;
        split2pack_2(yx, yy, ph, pm);
        *ytw0 = ph; *ytw1 = pm;
        *(float2*)&out[(size_t)row * (TT*32) + d0] = y0;
    }
    float kxs[5], kys[5];
    __syncthreads();

    #pragma unroll 1
    for (int step = 0; step < NSTEP; ++step) {
        const float h = __shfl(h_all, step);
        float bax = 0.f, bay = 0.f;

        #pragma unroll
        for (int s = 0; s < 6; ++s) {
            // ---- B1 fragment: direct from planes (no split) ----
            Frag2 B1;
            B1.h = __builtin_bit_cast(bf16x8, *ytr0);
            B1.m = __builtin_bit_cast(bf16x8, *ytr1);

            // ---- m1: 2 tiles (3-product) + tanh ----
            f32x4 z0 = mac2b(W1f[0], B1, b1f[0]);
            f32x4 z1 = mac2b(W1f[1], B1, b1f[1]);
            #pragma unroll
            for (int e = 0; e < 4; ++e) { z0[e] = tanh_fast(z0[e]); z1[e] = tanh_fast(z1[e]); }

            // ---- z in registers: D-frag == MFMA-16 B-frag (identity) ----
            Frag2s Z0 = split4_2(z0);
            Frag2s Z1 = split4_2(z1);

            // ---- m2: 2 d-tiles x (2 K-slices x 3 products) = 12 MFMA-16 ----
            const f32x4 zero = {0.f, 0.f, 0.f, 0.f};
            f32x4 p0, p1;
            {
                f32x4 a0 = zero, a1 = zero;
                a0 = MFMA16(W2f[0][0].h, Z0.h, a0);
                a1 = MFMA16(W2f[0][0].h, Z0.m, a1);
                a0 = MFMA16(W2f[0][0].m, Z0.h, a0);
                a1 = MFMA16(W2f[0][1].h, Z1.m, a1);
                a0 = MFMA16(W2f[0][1].h, Z1.h, a0);
                a0 = MFMA16(W2f[0][1].m, Z1.h, a0);
                #pragma unroll
                for (int i = 0; i < 4; ++i) p0[i] = a0[i] + a1[i];
            }
            {
                f32x4 a0 = zero, a1 = zero;
                a0 = MFMA16(W2f[1][0].h, Z0.h, a0);
                a1 = MFMA16(W2f[1][0].h, Z0.m, a1);
                a0 = MFMA16(W2f[1][0].m, Z0.h, a0);
                a1 = MFMA16(W2f[1][1].h, Z1.m, a1);
                a0 = MFMA16(W2f[1][1].h, Z1.h, a0);
                a0 = MFMA16(W2f[1][1].m, Z1.h, a0);
                #pragma unroll
                for (int i = 0; i < 4; ++i) p1[i] = a0[i] + a1[i];
            }
            *(f32x4*)pbw0 = p0;
            *(f32x4*)pbw1 = p1;
            __syncthreads();

            // ---- owner: reduce 4 partials, update, publish next yt planes ----
            float kx = b2x, ky = b2y;
            #pragma unroll
            for (int v4 = 0; v4 < 4; ++v4) {
                float2 pp = *(const float2*)&pred[v4 * 512];
                kx += pp.x; ky += pp.y;
            }
            if (s < 5) { kxs[s] = kx; kys[s] = ky; }
            bax = fmaf(BTc[s], kx, bax);
            bay = fmaf(BTc[s], ky, bay);

            float ytx, yty;
            if (s < 5) {
                float ax = ATc[s+1][s] * kx;
                float ay = ATc[s+1][s] * ky;
                #pragma unroll
                for (int j = 0; j < 5; ++j)
                    if (j < s) { ax = fmaf(ATc[s+1][j], kxs[j], ax);
                                 ay = fmaf(ATc[s+1][j], kys[j], ay); }
                ytx = fmaf(h, ax, yx);
                yty = fmaf(h, ay, yy);
            } else {
                yx = fmaf(h, bax, yx);
                yy = fmaf(h, bay, yy);
                ytx = yx; yty = yy;
                float2 yn = {yx, yy};
                *(float2*)&out[(size_t)row * (TT*32) + (size_t)(step+1) * 32 + d0] = yn;
            }
            unsigned int ph, pm;
            split2pack_2(ytx, yty, ph, pm);
            *ytw0 = ph; *ytw1 = pm;
            __syncthreads();
        }
    }
}

extern "C" void kernel_launch(void* const* d_in, const int* in_sizes, int n_in,
                              void* d_out, int out_size, void* d_ws, size_t ws_size,
                              hipStream_t stream) {
    (void)in_sizes; (void)n_in; (void)d_ws; (void)ws_size; (void)out_size;
    const float* x  = (const float*)d_in[0];
    const float* t  = (const float*)d_in[1];
    // d_in[2] = itv, d_in[3] = itv_mask : unused by the reference math
    const float* W1 = (const float*)d_in[4];
    const float* b1 = (const float*)d_in[5];
    const float* W2 = (const float*)d_in[6];
    const float* b2 = (const float*)d_in[7];
    float* out = (float*)d_out;

    dim3 grid(8192 / 16);   // 512 blocks x 4 waves (2 blocks/CU, R6 geometry)
    dim3 block(256);
    hipLaunchKernelGGL(NeuralODE_dopri5_r10, grid, block, 0, stream,
                       x, t, W1, b1, W2, b2, out);
}

// Round 11
// 302.682 us; speedup vs baseline: 2.2356x; 1.1546x over previous
//
#include <hip/hip_runtime.h>

#define TT 65
#define NSTEP 64

typedef __attribute__((ext_vector_type(8))) short bf16x8;
typedef __attribute__((ext_vector_type(4))) short bf16x4;
typedef __attribute__((ext_vector_type(4))) float f32x4;
typedef __attribute__((ext_vector_type(4))) unsigned int u32x4;
typedef __attribute__((ext_vector_type(2))) unsigned int u32x2;

// 16x16x16 bf16 MFMA builtin (name varies across ROCm versions) — R5/R9-verified
#if __has_builtin(__builtin_amdgcn_mfma_f32_16x16x16bf16_1k)
#define MFMA16(A,B,C) __builtin_amdgcn_mfma_f32_16x16x16bf16_1k((A),(B),(C),0,0,0)
#elif __has_builtin(__builtin_amdgcn_mfma_f32_16x16x16_bf16)
#define MFMA16(A,B,C) __builtin_amdgcn_mfma_f32_16x16x16_bf16((A),(B),(C),0,0,0)
#else
static __device__ __forceinline__ f32x4 mfma16_asm(bf16x4 a, bf16x4 b, f32x4 c) {
    f32x4 d;
    asm("v_mfma_f32_16x16x16_bf16 %0, %1, %2, %3" : "=v"(d) : "v"(a), "v"(b), "v"(c));
    return d;
}
#define MFMA16(A,B,C) mfma16_asm((A),(B),(C))
#endif

#define MFMA32(A,B,C) __builtin_amdgcn_mfma_f32_16x16x32_bf16((A),(B),(C),0,0,0)

__device__ constexpr float ATc[6][5] = {
    {0.f, 0.f, 0.f, 0.f, 0.f},
    {0.2f, 0.f, 0.f, 0.f, 0.f},
    {3.f/40.f, 9.f/40.f, 0.f, 0.f, 0.f},
    {44.f/45.f, -56.f/15.f, 32.f/9.f, 0.f, 0.f},
    {19372.f/6561.f, -25360.f/2187.f, 64448.f/6561.f, -212.f/729.f, 0.f},
    {9017.f/3168.f, -355.f/33.f, 46732.f/5247.f, 49.f/176.f, -5103.f/18656.f}
};
__device__ constexpr float BTc[6] = {35.f/384.f, 0.f, 500.f/1113.f, 125.f/192.f,
                                     -2187.f/6784.f, 11.f/84.f};

struct Frag2  { bf16x8 h, m; };
struct Frag2s { bf16x4 h, m; };

__device__ __forceinline__ float tanh_fast(float x) {
    float e = __expf(2.0f * x);
    return fmaf(-2.0f, __builtin_amdgcn_rcpf(e + 1.0f), 1.0f);
}

// pack hi16(b):hi16(a) in one v_perm_b32 (bytes 2,3 of a then 2,3 of b)
__device__ __forceinline__ unsigned int permhi(unsigned int b, unsigned int a) {
    return __builtin_amdgcn_perm(b, a, 0x07060302u);
}

// 2-term split: v = h + m + O(2^-17 |v|). h = trunc (residual exact);
// m = round-half-up of residual (+0x8000 carry).
__device__ __forceinline__ Frag2 split8_2(const float* v) {
    unsigned int wh[4], wm[4];
    #pragma unroll
    for (int p = 0; p < 4; ++p) {
        float a = v[2*p], b = v[2*p+1];
        unsigned int ua = __float_as_uint(a), ub = __float_as_uint(b);
        wh[p] = permhi(ub, ua);
        float ra = a - __uint_as_float(ua & 0xFFFF0000u);
        float rb = b - __uint_as_float(ub & 0xFFFF0000u);
        wm[p] = permhi(__float_as_uint(rb) + 0x8000u, __float_as_uint(ra) + 0x8000u);
    }
    Frag2 f;
    u32x4 H = {wh[0], wh[1], wh[2], wh[3]};
    u32x4 M = {wm[0], wm[1], wm[2], wm[3]};
    f.h = __builtin_bit_cast(bf16x8, H);
    f.m = __builtin_bit_cast(bf16x8, M);
    return f;
}

__device__ __forceinline__ Frag2s split4_2(f32x4 v) {
    unsigned int wh[2], wm[2];
    #pragma unroll
    for (int p = 0; p < 2; ++p) {
        float a = v[2*p], b = v[2*p+1];
        unsigned int ua = __float_as_uint(a), ub = __float_as_uint(b);
        wh[p] = permhi(ub, ua);
        float ra = a - __uint_as_float(ua & 0xFFFF0000u);
        float rb = b - __uint_as_float(ub & 0xFFFF0000u);
        wm[p] = permhi(__float_as_uint(rb) + 0x8000u, __float_as_uint(ra) + 0x8000u);
    }
    Frag2s f;
    u32x2 H = {wh[0], wh[1]};
    u32x2 M = {wm[0], wm[1]};
    f.h = __builtin_bit_cast(bf16x4, H);
    f.m = __builtin_bit_cast(bf16x4, M);
    return f;
}

__device__ __forceinline__ void split2pack_2(float a, float b,
                                             unsigned int& ph, unsigned int& pm) {
    unsigned int ua = __float_as_uint(a), ub = __float_as_uint(b);
    ph = permhi(ub, ua);
    float ra = a - __uint_as_float(ua & 0xFFFF0000u);
    float rb = b - __uint_as_float(ub & 0xFFFF0000u);
    pm = permhi(__float_as_uint(rb) + 0x8000u, __float_as_uint(ra) + 0x8000u);
}

// Block = 4 waves = 16 rows, grid 512 (2 blocks/CU) — R6/R10 geometry (proven
// optimum: two independent blocks per CU self-overlap across barriers).
// R11 deltas vs R10 (work-cut only, structure frozen):
//   single-chain MFMA accumulation (no merge adds; chains run at full rate),
//   v_perm-based split packing, b2 folded into wave-0's m2 accumulator init.
__global__ __launch_bounds__(256, 2)
void NeuralODE_dopri5_r11(const float* __restrict__ x, const float* __restrict__ tptr,
                          const float* __restrict__ W1, const float* __restrict__ b1,
                          const float* __restrict__ W2, const float* __restrict__ b2,
                          float* __restrict__ out)
{
    __shared__ unsigned int ytp[2][16][16];          // yt planes h/m: 2 KB
    __shared__ __align__(16) float pb[4][512];       // m2 partials: 8 KB

    const int tid = threadIdx.x;
    const int w   = tid >> 6;
    const int l   = tid & 63;
    const int r   = l & 15;
    const int q   = l >> 4;
    const int g   = (r >> 1) & 3;                    // plane block swizzle (R6-proven)
    const int swz = (r & 7) << 2;                    // f32-block swizzle (R4-proven)
    const int row = blockIdx.x * 16 + r;
    const int d0  = 8 * w + 2 * q;                   // owned state pair

    // ---- static weight fragments ----
    Frag2 W1f[2];
    f32x4 b1f[2];
    {
        float v[8];
        #pragma unroll
        for (int i = 0; i < 2; ++i) {
            int m = 2 * w + i;
            *(f32x4*)&v[0] = *(const f32x4*)&W1[(16*m + r) * 32 + 8*q];
            *(f32x4*)&v[4] = *(const f32x4*)&W1[(16*m + r) * 32 + 8*q + 4];
            W1f[i] = split8_2(v);
            b1f[i] = *(const f32x4*)&b1[16*m + 4*q];
        }
    }
    // W2 fragments for MFMA-16: A[r][4q+j] = W2[16dt + r][32w + 16ks + 4q + j]
    Frag2s W2f[2][2];
    #pragma unroll
    for (int dt = 0; dt < 2; ++dt)
        #pragma unroll
        for (int ks = 0; ks < 2; ++ks) {
            f32x4 v = *(const f32x4*)&W2[(16*dt + r) * 128 + 32*w + 16*ks + 4*q];
            W2f[dt][ks] = split4_2(v);
        }
    // b2 folded into wave-0's m2 accumulator init (C-operand); other waves zero.
    const f32x4 zero = {0.f, 0.f, 0.f, 0.f};
    f32x4 acc_init[2];
    #pragma unroll
    for (int dt = 0; dt < 2; ++dt)
        acc_init[dt] = (w == 0) ? *(const f32x4*)&b2[16*dt + 4*q] : zero;

    // ---- loop-invariant LDS addresses ----
    unsigned int* const ytw0 = &ytp[0][r][((w ^ g) << 2) + q];
    unsigned int* const ytw1 = &ytp[1][r][((w ^ g) << 2) + q];
    const u32x4* const ytr0 = (const u32x4*)&ytp[0][r][(q ^ g) << 2];
    const u32x4* const ytr1 = (const u32x4*)&ytp[1][r][(q ^ g) << 2];
    float* const pbw0 = &pb[w][r * 32 + ((     4*q) ^ swz)];
    float* const pbw1 = &pb[w][r * 32 + ((16 + 4*q) ^ swz)];
    const float* const pred = &pb[0][r * 32 + (d0 ^ swz)];   // + 512*v

    const float h_all = tptr[l + 1] - tptr[l];   // t row 0 uniform; lane s has h_s

    // ---- state init ----
    float2 y0 = *(const float2*)&x[(size_t)row * (TT*32) + d0];
    float yx = y0.x, yy = y0.y;
    {
        unsigned int ph, pm;
        split2pack_2(yx, yy, ph, pm);
        *ytw0 = ph; *ytw1 = pm;
        *(float2*)&out[(size_t)row * (TT*32) + d0] = y0;
    }
    float kxs[5], kys[5];
    __syncthreads();

    #pragma unroll 1
    for (int step = 0; step < NSTEP; ++step) {
        const float h = __shfl(h_all, step);
        float bax = 0.f, bay = 0.f;

        #pragma unroll
        for (int s = 0; s < 6; ++s) {
            // ---- B1 fragment: direct from planes (no split) ----
            Frag2 B1;
            B1.h = __builtin_bit_cast(bf16x8, *ytr0);
            B1.m = __builtin_bit_cast(bf16x8, *ytr1);

            // ---- m1: 2 tiles, single 3-MFMA chains (no merges) + tanh ----
            f32x4 z0 = b1f[0];
            z0 = MFMA32(W1f[0].h, B1.h, z0);
            z0 = MFMA32(W1f[0].h, B1.m, z0);
            z0 = MFMA32(W1f[0].m, B1.h, z0);
            f32x4 z1 = b1f[1];
            z1 = MFMA32(W1f[1].h, B1.h, z1);
            z1 = MFMA32(W1f[1].h, B1.m, z1);
            z1 = MFMA32(W1f[1].m, B1.h, z1);
            #pragma unroll
            for (int e = 0; e < 4; ++e) { z0[e] = tanh_fast(z0[e]); z1[e] = tanh_fast(z1[e]); }

            // ---- z in registers: D-frag == MFMA-16 B-frag (identity) ----
            Frag2s Z0 = split4_2(z0);
            Frag2s Z1 = split4_2(z1);

            // ---- m2: 2 d-tiles, single 6-MFMA chains, b2 pre-folded ----
            f32x4 p0 = acc_init[0];
            p0 = MFMA16(W2f[0][0].h, Z0.h, p0);
            p0 = MFMA16(W2f[0][0].h, Z0.m, p0);
            p0 = MFMA16(W2f[0][0].m, Z0.h, p0);
            p0 = MFMA16(W2f[0][1].h, Z1.h, p0);
            p0 = MFMA16(W2f[0][1].h, Z1.m, p0);
            p0 = MFMA16(W2f[0][1].m, Z1.h, p0);
            f32x4 p1 = acc_init[1];
            p1 = MFMA16(W2f[1][0].h, Z0.h, p1);
            p1 = MFMA16(W2f[1][0].h, Z0.m, p1);
            p1 = MFMA16(W2f[1][0].m, Z0.h, p1);
            p1 = MFMA16(W2f[1][1].h, Z1.h, p1);
            p1 = MFMA16(W2f[1][1].h, Z1.m, p1);
            p1 = MFMA16(W2f[1][1].m, Z1.h, p1);
            *(f32x4*)pbw0 = p0;
            *(f32x4*)pbw1 = p1;
            __syncthreads();

            // ---- owner: reduce 4 partials (b2 already in), update, publish ----
            float2 pp0 = *(const float2*)&pred[0 * 512];
            float2 pp1 = *(const float2*)&pred[1 * 512];
            float2 pp2 = *(const float2*)&pred[2 * 512];
            float2 pp3 = *(const float2*)&pred[3 * 512];
            float kx = (pp0.x + pp1.x) + (pp2.x + pp3.x);
            float ky = (pp0.y + pp1.y) + (pp2.y + pp3.y);
            if (s < 5) { kxs[s] = kx; kys[s] = ky; }
            bax = fmaf(BTc[s], kx, bax);
            bay = fmaf(BTc[s], ky, bay);

            float ytx, yty;
            if (s < 5) {
                float ax = ATc[s+1][s] * kx;
                float ay = ATc[s+1][s] * ky;
                #pragma unroll
                for (int j = 0; j < 5; ++j)
                    if (j < s) { ax = fmaf(ATc[s+1][j], kxs[j], ax);
                                 ay = fmaf(ATc[s+1][j], kys[j], ay); }
                ytx = fmaf(h, ax, yx);
                yty = fmaf(h, ay, yy);
            } else {
                yx = fmaf(h, bax, yx);
                yy = fmaf(h, bay, yy);
                ytx = yx; yty = yy;
                float2 yn = {yx, yy};
                *(float2*)&out[(size_t)row * (TT*32) + (size_t)(step+1) * 32 + d0] = yn;
            }
            unsigned int ph, pm;
            split2pack_2(ytx, yty, ph, pm);
            *ytw0 = ph; *ytw1 = pm;
            __syncthreads();
        }
    }
}

extern "C" void kernel_launch(void* const* d_in, const int* in_sizes, int n_in,
                              void* d_out, int out_size, void* d_ws, size_t ws_size,
                              hipStream_t stream) {
    (void)in_sizes; (void)n_in; (void)d_ws; (void)ws_size; (void)out_size;
    const float* x  = (const float*)d_in[0];
    const float* t  = (const float*)d_in[1];
    // d_in[2] = itv, d_in[3] = itv_mask : unused by the reference math
    const float* W1 = (const float*)d_in[4];
    const float* b1 = (const float*)d_in[5];
    const float* W2 = (const float*)d_in[6];
    const float* b2 = (const float*)d_in[7];
    float* out = (float*)d_out;

    dim3 grid(8192 / 16);   // 512 blocks x 4 waves (2 blocks/CU, R6 geometry)
    dim3 block(256);
    hipLaunchKernelGGL(NeuralODE_dopri5_r11, grid, block, 0, stream,
                       x, t, W1, b1, W2, b2, out);
}

// Round 12
// 275.633 us; speedup vs baseline: 2.4549x; 1.0981x over previous
//
#include <hip/hip_runtime.h>

#define TT 65
#define NSTEP 64

typedef __attribute__((ext_vector_type(8))) short bf16x8;
typedef __attribute__((ext_vector_type(4))) float f32x4;
typedef __attribute__((ext_vector_type(4))) unsigned int u32x4;

#define MFMA32(A,B,C) __builtin_amdgcn_mfma_f32_16x16x32_bf16((A),(B),(C),0,0,0)

// native exp2 (single trans op); fallback keeps correctness if builtin absent
#if __has_builtin(__builtin_amdgcn_exp2f)
#define EXP2F(x) __builtin_amdgcn_exp2f(x)
#else
#define EXP2F(x) __expf(0.6931471805599453f * (x))
#endif

__device__ constexpr float ATc[6][5] = {
    {0.f, 0.f, 0.f, 0.f, 0.f},
    {0.2f, 0.f, 0.f, 0.f, 0.f},
    {3.f/40.f, 9.f/40.f, 0.f, 0.f, 0.f},
    {44.f/45.f, -56.f/15.f, 32.f/9.f, 0.f, 0.f},
    {19372.f/6561.f, -25360.f/2187.f, 64448.f/6561.f, -212.f/729.f, 0.f},
    {9017.f/3168.f, -355.f/33.f, 46732.f/5247.f, 49.f/176.f, -5103.f/18656.f}
};
__device__ constexpr float BTc[6] = {35.f/384.f, 0.f, 500.f/1113.f, 125.f/192.f,
                                     -2187.f/6784.f, 11.f/84.f};

struct Frag2 { bf16x8 h, m; };

__device__ __forceinline__ float tanh_fast(float x) {
    // tanh(x) = 1 - 2/(exp(2x)+1); exp(2x) = exp2(x * 2*log2(e))
    float e = EXP2F(x * 2.8853900817779268f);
    return fmaf(-2.0f, __builtin_amdgcn_rcpf(e + 1.0f), 1.0f);
}

// pack hi16(b):hi16(a) in one v_perm_b32 (bytes 2,3 of a then 2,3 of b)
__device__ __forceinline__ unsigned int permhi(unsigned int b, unsigned int a) {
    return __builtin_amdgcn_perm(b, a, 0x07060302u);
}

// 2-term split: v = h + m + O(2^-17 |v|). h = trunc (residual exact);
// m = round-half-up of residual (+0x8000 carry).
__device__ __forceinline__ void splitpair(float a, float b,
                                          unsigned int& ph, unsigned int& pm) {
    unsigned int ua = __float_as_uint(a), ub = __float_as_uint(b);
    ph = permhi(ub, ua);
    float ra = a - __uint_as_float(ua & 0xFFFF0000u);
    float rb = b - __uint_as_float(ub & 0xFFFF0000u);
    pm = permhi(__float_as_uint(rb) + 0x8000u, __float_as_uint(ra) + 0x8000u);
}

__device__ __forceinline__ Frag2 split8_2(const float* v) {
    unsigned int wh[4], wm[4];
    #pragma unroll
    for (int p = 0; p < 4; ++p) splitpair(v[2*p], v[2*p+1], wh[p], wm[p]);
    Frag2 f;
    u32x4 H = {wh[0], wh[1], wh[2], wh[3]};
    u32x4 M = {wm[0], wm[1], wm[2], wm[3]};
    f.h = __builtin_bit_cast(bf16x8, H);
    f.m = __builtin_bit_cast(bf16x8, M);
    return f;
}

// split two f32x4 z-tiles directly into a concat'd MFMA32 B-fragment
__device__ __forceinline__ Frag2 split44_2(f32x4 a, f32x4 b) {
    unsigned int wh[4], wm[4];
    splitpair(a[0], a[1], wh[0], wm[0]);
    splitpair(a[2], a[3], wh[1], wm[1]);
    splitpair(b[0], b[1], wh[2], wm[2]);
    splitpair(b[2], b[3], wh[3], wm[3]);
    Frag2 f;
    u32x4 H = {wh[0], wh[1], wh[2], wh[3]};
    u32x4 M = {wm[0], wm[1], wm[2], wm[3]};
    f.h = __builtin_bit_cast(bf16x8, H);
    f.m = __builtin_bit_cast(bf16x8, M);
    return f;
}

// Block = 4 waves = 16 rows, grid 512 (2 blocks/CU) — R6/R10/R11 geometry
// (proven optimum). R12 deltas vs R11 (work-cut only):
//   m2 via 6 MFMA 16x16x32 with K-axis permutation sigma(8q+j) = {4q+j,
//   16+4q+j-4}: B-frag = concat(Z0, Z1) (zero shuffles, z D-frag identity),
//   A-frag = W2 loaded with the same permutation. Halves m2 issue slots.
//   tanh uses native exp2 (one mul + one trans).
__global__ __launch_bounds__(256, 2)
void NeuralODE_dopri5_r12(const float* __restrict__ x, const float* __restrict__ tptr,
                          const float* __restrict__ W1, const float* __restrict__ b1,
                          const float* __restrict__ W2, const float* __restrict__ b2,
                          float* __restrict__ out)
{
    __shared__ unsigned int ytp[2][16][16];          // yt planes h/m: 2 KB
    __shared__ __align__(16) float pb[4][512];       // m2 partials: 8 KB

    const int tid = threadIdx.x;
    const int w   = tid >> 6;
    const int l   = tid & 63;
    const int r   = l & 15;
    const int q   = l >> 4;
    const int g   = (r >> 1) & 3;                    // plane block swizzle (R6-proven)
    const int swz = (r & 7) << 2;                    // f32-block swizzle (R4-proven)
    const int row = blockIdx.x * 16 + r;
    const int d0  = 8 * w + 2 * q;                   // owned state pair

    // ---- static weight fragments ----
    Frag2 W1f[2];
    f32x4 b1f[2];
    {
        float v[8];
        #pragma unroll
        for (int i = 0; i < 2; ++i) {
            int m = 2 * w + i;
            *(f32x4*)&v[0] = *(const f32x4*)&W1[(16*m + r) * 32 + 8*q];
            *(f32x4*)&v[4] = *(const f32x4*)&W1[(16*m + r) * 32 + 8*q + 4];
            W1f[i] = split8_2(v);
            b1f[i] = *(const f32x4*)&b1[16*m + 4*q];
        }
    }
    // W2 A-fragments with the sigma K-permutation:
    //   A[r][8q+j] = W2[16dt + r][32w + (j<4 ? 4q+j : 16 + 4q + j-4)]
    Frag2 W2f[2];
    {
        float v[8];
        #pragma unroll
        for (int dt = 0; dt < 2; ++dt) {
            *(f32x4*)&v[0] = *(const f32x4*)&W2[(16*dt + r) * 128 + 32*w + 4*q];
            *(f32x4*)&v[4] = *(const f32x4*)&W2[(16*dt + r) * 128 + 32*w + 16 + 4*q];
            W2f[dt] = split8_2(v);
        }
    }
    // b2 folded into wave-0's m2 accumulator init (C-operand); other waves zero.
    const f32x4 zero = {0.f, 0.f, 0.f, 0.f};
    f32x4 acc_init[2];
    #pragma unroll
    for (int dt = 0; dt < 2; ++dt)
        acc_init[dt] = (w == 0) ? *(const f32x4*)&b2[16*dt + 4*q] : zero;

    // ---- loop-invariant LDS addresses ----
    unsigned int* const ytw0 = &ytp[0][r][((w ^ g) << 2) + q];
    unsigned int* const ytw1 = &ytp[1][r][((w ^ g) << 2) + q];
    const u32x4* const ytr0 = (const u32x4*)&ytp[0][r][(q ^ g) << 2];
    const u32x4* const ytr1 = (const u32x4*)&ytp[1][r][(q ^ g) << 2];
    float* const pbw0 = &pb[w][r * 32 + ((     4*q) ^ swz)];
    float* const pbw1 = &pb[w][r * 32 + ((16 + 4*q) ^ swz)];
    const float* const pred = &pb[0][r * 32 + (d0 ^ swz)];   // + 512*v

    const float h_all = tptr[l + 1] - tptr[l];   // t row 0 uniform; lane s has h_s

    // ---- state init ----
    float2 y0 = *(const float2*)&x[(size_t)row * (TT*32) + d0];
    float yx = y0.x, yy = y0.y;
    {
        unsigned int ph, pm;
        splitpair(yx, yy, ph, pm);
        *ytw0 = ph; *ytw1 = pm;
        *(float2*)&out[(size_t)row * (TT*32) + d0] = y0;
    }
    float kxs[5], kys[5];
    __syncthreads();

    #pragma unroll 1
    for (int step = 0; step < NSTEP; ++step) {
        const float h = __shfl(h_all, step);
        float bax = 0.f, bay = 0.f;

        #pragma unroll
        for (int s = 0; s < 6; ++s) {
            // ---- B1 fragment: direct from planes (no split) ----
            Frag2 B1;
            B1.h = __builtin_bit_cast(bf16x8, *ytr0);
            B1.m = __builtin_bit_cast(bf16x8, *ytr1);

            // ---- m1: 2 tiles, single 3-MFMA chains + tanh ----
            f32x4 z0 = b1f[0];
            z0 = MFMA32(W1f[0].h, B1.h, z0);
            z0 = MFMA32(W1f[0].h, B1.m, z0);
            z0 = MFMA32(W1f[0].m, B1.h, z0);
            f32x4 z1 = b1f[1];
            z1 = MFMA32(W1f[1].h, B1.h, z1);
            z1 = MFMA32(W1f[1].h, B1.m, z1);
            z1 = MFMA32(W1f[1].m, B1.h, z1);
            #pragma unroll
            for (int e = 0; e < 4; ++e) { z0[e] = tanh_fast(z0[e]); z1[e] = tanh_fast(z1[e]); }

            // ---- z -> concat'd MFMA32 B-fragment (identity + sigma) ----
            Frag2 Z = split44_2(z0, z1);

            // ---- m2: 2 d-tiles x 3 products, K=32 in one MFMA each ----
            f32x4 p0 = acc_init[0];
            p0 = MFMA32(W2f[0].h, Z.h, p0);
            p0 = MFMA32(W2f[0].h, Z.m, p0);
            p0 = MFMA32(W2f[0].m, Z.h, p0);
            f32x4 p1 = acc_init[1];
            p1 = MFMA32(W2f[1].h, Z.h, p1);
            p1 = MFMA32(W2f[1].h, Z.m, p1);
            p1 = MFMA32(W2f[1].m, Z.h, p1);
            *(f32x4*)pbw0 = p0;
            *(f32x4*)pbw1 = p1;
            __syncthreads();

            // ---- owner: reduce 4 partials (b2 already in), update, publish ----
            float2 pp0 = *(const float2*)&pred[0 * 512];
            float2 pp1 = *(const float2*)&pred[1 * 512];
            float2 pp2 = *(const float2*)&pred[2 * 512];
            float2 pp3 = *(const float2*)&pred[3 * 512];
            float kx = (pp0.x + pp1.x) + (pp2.x + pp3.x);
            float ky = (pp0.y + pp1.y) + (pp2.y + pp3.y);
            if (s < 5) { kxs[s] = kx; kys[s] = ky; }
            bax = fmaf(BTc[s], kx, bax);
            bay = fmaf(BTc[s], ky, bay);

            float ytx, yty;
            if (s < 5) {
                float ax = ATc[s+1][s] * kx;
                float ay = ATc[s+1][s] * ky;
                #pragma unroll
                for (int j = 0; j < 5; ++j)
                    if (j < s) { ax = fmaf(ATc[s+1][j], kxs[j], ax);
                                 ay = fmaf(ATc[s+1][j], kys[j], ay); }
                ytx = fmaf(h, ax, yx);
                yty = fmaf(h, ay, yy);
            } else {
                yx = fmaf(h, bax, yx);
                yy = fmaf(h, bay, yy);
                ytx = yx; yty = yy;
                float2 yn = {yx, yy};
                *(float2*)&out[(size_t)row * (TT*32) + (size_t)(step+1) * 32 + d0] = yn;
            }
            unsigned int ph, pm;
            splitpair(ytx, yty, ph, pm);
            *ytw0 = ph; *ytw1 = pm;
            __syncthreads();
        }
    }
}

extern "C" void kernel_launch(void* const* d_in, const int* in_sizes, int n_in,
                              void* d_out, int out_size, void* d_ws, size_t ws_size,
                              hipStream_t stream) {
    (void)in_sizes; (void)n_in; (void)d_ws; (void)ws_size; (void)out_size;
    const float* x  = (const float*)d_in[0];
    const float* t  = (const float*)d_in[1];
    // d_in[2] = itv, d_in[3] = itv_mask : unused by the reference math
    const float* W1 = (const float*)d_in[4];
    const float* b1 = (const float*)d_in[5];
    const float* W2 = (const float*)d_in[6];
    const float* b2 = (const float*)d_in[7];
    float* out = (float*)d_out;

    dim3 grid(8192 / 16);   // 512 blocks x 4 waves (2 blocks/CU, R6 geometry)
    dim3 block(256);
    hipLaunchKernelGGL(NeuralODE_dopri5_r12, grid, block, 0, stream,
                       x, t, W1, b1, W2, b2, out);
}

// Round 13
// 238.799 us; speedup vs baseline: 2.8336x; 1.1542x over previous
//
#include <hip/hip_runtime.h>

#define TT 65
#define NSTEP 64

typedef __attribute__((ext_vector_type(8))) short bf16x8;
typedef __attribute__((ext_vector_type(4))) float f32x4;
typedef __attribute__((ext_vector_type(4))) unsigned int u32x4;

#define MFMA32(A,B,C) __builtin_amdgcn_mfma_f32_16x16x32_bf16((A),(B),(C),0,0,0)

// native exp2 (single trans op); fallback keeps correctness if builtin absent
#if __has_builtin(__builtin_amdgcn_exp2f)
#define EXP2F(x) __builtin_amdgcn_exp2f(x)
#else
#define EXP2F(x) __expf(0.6931471805599453f * (x))
#endif

__device__ constexpr float ATc[6][5] = {
    {0.f, 0.f, 0.f, 0.f, 0.f},
    {0.2f, 0.f, 0.f, 0.f, 0.f},
    {3.f/40.f, 9.f/40.f, 0.f, 0.f, 0.f},
    {44.f/45.f, -56.f/15.f, 32.f/9.f, 0.f, 0.f},
    {19372.f/6561.f, -25360.f/2187.f, 64448.f/6561.f, -212.f/729.f, 0.f},
    {9017.f/3168.f, -355.f/33.f, 46732.f/5247.f, 49.f/176.f, -5103.f/18656.f}
};
__device__ constexpr float BTc[6] = {35.f/384.f, 0.f, 500.f/1113.f, 125.f/192.f,
                                     -2187.f/6784.f, 11.f/84.f};

struct Frag2 { bf16x8 h, m; };

__device__ __forceinline__ float tanh_fast(float x) {
    // tanh(x) = 1 - 2/(exp(2x)+1); exp(2x) = exp2(x * 2*log2(e))
    float e = EXP2F(x * 2.8853900817779268f);
    return fmaf(-2.0f, __builtin_amdgcn_rcpf(e + 1.0f), 1.0f);
}

// pack hi16(b):hi16(a) in one v_perm_b32 (bytes 2,3 of a then 2,3 of b)
__device__ __forceinline__ unsigned int permhi(unsigned int b, unsigned int a) {
    return __builtin_amdgcn_perm(b, a, 0x07060302u);
}

// 2-term split: v = h + m + O(2^-17 |v|). h = trunc (residual exact);
// m = round-half-up of residual (+0x8000 carry).
__device__ __forceinline__ void splitpair(float a, float b,
                                          unsigned int& ph, unsigned int& pm) {
    unsigned int ua = __float_as_uint(a), ub = __float_as_uint(b);
    ph = permhi(ub, ua);
    float ra = a - __uint_as_float(ua & 0xFFFF0000u);
    float rb = b - __uint_as_float(ub & 0xFFFF0000u);
    pm = permhi(__float_as_uint(rb) + 0x8000u, __float_as_uint(ra) + 0x8000u);
}

__device__ __forceinline__ Frag2 split8_2(const float* v) {
    unsigned int wh[4], wm[4];
    #pragma unroll
    for (int p = 0; p < 4; ++p) splitpair(v[2*p], v[2*p+1], wh[p], wm[p]);
    Frag2 f;
    u32x4 H = {wh[0], wh[1], wh[2], wh[3]};
    u32x4 M = {wm[0], wm[1], wm[2], wm[3]};
    f.h = __builtin_bit_cast(bf16x8, H);
    f.m = __builtin_bit_cast(bf16x8, M);
    return f;
}

// R13: z packed to a SINGLE bf16 plane (round-half-up), no m-plane.
// |z| < 1 so |delta z| <= 2^-9; m2 error = W2 . delta z (the declared bet).
__device__ __forceinline__ bf16x8 packz(f32x4 a, f32x4 b) {
    unsigned int w0 = permhi(__float_as_uint(a[1]) + 0x8000u,
                             __float_as_uint(a[0]) + 0x8000u);
    unsigned int w1 = permhi(__float_as_uint(a[3]) + 0x8000u,
                             __float_as_uint(a[2]) + 0x8000u);
    unsigned int w2 = permhi(__float_as_uint(b[1]) + 0x8000u,
                             __float_as_uint(b[0]) + 0x8000u);
    unsigned int w3 = permhi(__float_as_uint(b[3]) + 0x8000u,
                             __float_as_uint(b[2]) + 0x8000u);
    u32x4 H = {w0, w1, w2, w3};
    return __builtin_bit_cast(bf16x8, H);
}

// Block = 4 waves = 16 rows, grid 512 (2 blocks/CU) — R6..R12 geometry (proven
// optimum). R13 delta vs R12 (work-cut, numerics bet):
//   m2 = (W2h + W2m) . Zh : z single-plane (drop Zm product + m-plane packing).
//   Everything else identical to R12.
__global__ __launch_bounds__(256, 2)
void NeuralODE_dopri5_r13(const float* __restrict__ x, const float* __restrict__ tptr,
                          const float* __restrict__ W1, const float* __restrict__ b1,
                          const float* __restrict__ W2, const float* __restrict__ b2,
                          float* __restrict__ out)
{
    __shared__ unsigned int ytp[2][16][16];          // yt planes h/m: 2 KB
    __shared__ __align__(16) float pb[4][512];       // m2 partials: 8 KB

    const int tid = threadIdx.x;
    const int w   = tid >> 6;
    const int l   = tid & 63;
    const int r   = l & 15;
    const int q   = l >> 4;
    const int g   = (r >> 1) & 3;                    // plane block swizzle (R6-proven)
    const int swz = (r & 7) << 2;                    // f32-block swizzle (R4-proven)
    const int row = blockIdx.x * 16 + r;
    const int d0  = 8 * w + 2 * q;                   // owned state pair

    // ---- static weight fragments ----
    Frag2 W1f[2];
    f32x4 b1f[2];
    {
        float v[8];
        #pragma unroll
        for (int i = 0; i < 2; ++i) {
            int m = 2 * w + i;
            *(f32x4*)&v[0] = *(const f32x4*)&W1[(16*m + r) * 32 + 8*q];
            *(f32x4*)&v[4] = *(const f32x4*)&W1[(16*m + r) * 32 + 8*q + 4];
            W1f[i] = split8_2(v);
            b1f[i] = *(const f32x4*)&b1[16*m + 4*q];
        }
    }
    // W2 A-fragments with the sigma K-permutation:
    //   A[r][8q+j] = W2[16dt + r][32w + (j<4 ? 4q+j : 16 + 4q + j-4)]
    Frag2 W2f[2];
    {
        float v[8];
        #pragma unroll
        for (int dt = 0; dt < 2; ++dt) {
            *(f32x4*)&v[0] = *(const f32x4*)&W2[(16*dt + r) * 128 + 32*w + 4*q];
            *(f32x4*)&v[4] = *(const f32x4*)&W2[(16*dt + r) * 128 + 32*w + 16 + 4*q];
            W2f[dt] = split8_2(v);
        }
    }
    // b2 folded into wave-0's m2 accumulator init (C-operand); other waves zero.
    const f32x4 zero = {0.f, 0.f, 0.f, 0.f};
    f32x4 acc_init[2];
    #pragma unroll
    for (int dt = 0; dt < 2; ++dt)
        acc_init[dt] = (w == 0) ? *(const f32x4*)&b2[16*dt + 4*q] : zero;

    // ---- loop-invariant LDS addresses ----
    unsigned int* const ytw0 = &ytp[0][r][((w ^ g) << 2) + q];
    unsigned int* const ytw1 = &ytp[1][r][((w ^ g) << 2) + q];
    const u32x4* const ytr0 = (const u32x4*)&ytp[0][r][(q ^ g) << 2];
    const u32x4* const ytr1 = (const u32x4*)&ytp[1][r][(q ^ g) << 2];
    float* const pbw0 = &pb[w][r * 32 + ((     4*q) ^ swz)];
    float* const pbw1 = &pb[w][r * 32 + ((16 + 4*q) ^ swz)];
    const float* const pred = &pb[0][r * 32 + (d0 ^ swz)];   // + 512*v

    const float h_all = tptr[l + 1] - tptr[l];   // t row 0 uniform; lane s has h_s

    // ---- state init ----
    float2 y0 = *(const float2*)&x[(size_t)row * (TT*32) + d0];
    float yx = y0.x, yy = y0.y;
    {
        unsigned int ph, pm;
        splitpair(yx, yy, ph, pm);
        *ytw0 = ph; *ytw1 = pm;
        *(float2*)&out[(size_t)row * (TT*32) + d0] = y0;
    }
    float kxs[5], kys[5];
    __syncthreads();

    #pragma unroll 1
    for (int step = 0; step < NSTEP; ++step) {
        const float h = __shfl(h_all, step);
        float bax = 0.f, bay = 0.f;

        #pragma unroll
        for (int s = 0; s < 6; ++s) {
            // ---- B1 fragment: direct from planes (no split) ----
            Frag2 B1;
            B1.h = __builtin_bit_cast(bf16x8, *ytr0);
            B1.m = __builtin_bit_cast(bf16x8, *ytr1);

            // ---- m1: 2 tiles, single 3-MFMA chains + tanh ----
            f32x4 z0 = b1f[0];
            z0 = MFMA32(W1f[0].h, B1.h, z0);
            z0 = MFMA32(W1f[0].h, B1.m, z0);
            z0 = MFMA32(W1f[0].m, B1.h, z0);
            f32x4 z1 = b1f[1];
            z1 = MFMA32(W1f[1].h, B1.h, z1);
            z1 = MFMA32(W1f[1].h, B1.m, z1);
            z1 = MFMA32(W1f[1].m, B1.h, z1);
            #pragma unroll
            for (int e = 0; e < 4; ++e) { z0[e] = tanh_fast(z0[e]); z1[e] = tanh_fast(z1[e]); }

            // ---- z -> single-plane MFMA32 B-fragment (sigma concat) ----
            bf16x8 Zh = packz(z0, z1);

            // ---- m2: 2 d-tiles x 2 products, K=32 ----
            f32x4 p0 = acc_init[0];
            p0 = MFMA32(W2f[0].h, Zh, p0);
            p0 = MFMA32(W2f[0].m, Zh, p0);
            f32x4 p1 = acc_init[1];
            p1 = MFMA32(W2f[1].h, Zh, p1);
            p1 = MFMA32(W2f[1].m, Zh, p1);
            *(f32x4*)pbw0 = p0;
            *(f32x4*)pbw1 = p1;
            __syncthreads();

            // ---- owner: reduce 4 partials (b2 already in), update, publish ----
            float2 pp0 = *(const float2*)&pred[0 * 512];
            float2 pp1 = *(const float2*)&pred[1 * 512];
            float2 pp2 = *(const float2*)&pred[2 * 512];
            float2 pp3 = *(const float2*)&pred[3 * 512];
            float kx = (pp0.x + pp1.x) + (pp2.x + pp3.x);
            float ky = (pp0.y + pp1.y) + (pp2.y + pp3.y);
            if (s < 5) { kxs[s] = kx; kys[s] = ky; }
            bax = fmaf(BTc[s], kx, bax);
            bay = fmaf(BTc[s], ky, bay);

            float ytx, yty;
            if (s < 5) {
                float ax = ATc[s+1][s] * kx;
                float ay = ATc[s+1][s] * ky;
                #pragma unroll
                for (int j = 0; j < 5; ++j)
                    if (j < s) { ax = fmaf(ATc[s+1][j], kxs[j], ax);
                                 ay = fmaf(ATc[s+1][j], kys[j], ay); }
                ytx = fmaf(h, ax, yx);
                yty = fmaf(h, ay, yy);
            } else {
                yx = fmaf(h, bax, yx);
                yy = fmaf(h, bay, yy);
                ytx = yx; yty = yy;
                float2 yn = {yx, yy};
                *(float2*)&out[(size_t)row * (TT*32) + (size_t)(step+1) * 32 + d0] = yn;
            }
            unsigned int ph, pm;
            splitpair(ytx, yty, ph, pm);
            *ytw0 = ph; *ytw1 = pm;
            __syncthreads();
        }
    }
}

extern "C" void kernel_launch(void* const* d_in, const int* in_sizes, int n_in,
                              void* d_out, int out_size, void* d_ws, size_t ws_size,
                              hipStream_t stream) {
    (void)in_sizes; (void)n_in; (void)d_ws; (void)ws_size; (void)out_size;
    const float* x  = (const float*)d_in[0];
    const float* t  = (const float*)d_in[1];
    // d_in[2] = itv, d_in[3] = itv_mask : unused by the reference math
    const float* W1 = (const float*)d_in[4];
    const float* b1 = (const float*)d_in[5];
    const float* W2 = (const float*)d_in[6];
    const float* b2 = (const float*)d_in[7];
    float* out = (float*)d_out;

    dim3 grid(8192 / 16);   // 512 blocks x 4 waves (2 blocks/CU, R6 geometry)
    dim3 block(256);
    hipLaunchKernelGGL(NeuralODE_dopri5_r13, grid, block, 0, stream,
                       x, t, W1, b1, W2, b2, out);
}

// Round 14
// 235.256 us; speedup vs baseline: 2.8763x; 1.0151x over previous
//
#include <hip/hip_runtime.h>

#define TT 65
#define NSTEP 64

typedef __attribute__((ext_vector_type(8))) short bf16x8;
typedef __attribute__((ext_vector_type(4))) float f32x4;
typedef __attribute__((ext_vector_type(4))) unsigned int u32x4;

#define MFMA32(A,B,C) __builtin_amdgcn_mfma_f32_16x16x32_bf16((A),(B),(C),0,0,0)

// native exp2 (single trans op); fallback keeps correctness if builtin absent
#if __has_builtin(__builtin_amdgcn_exp2f)
#define EXP2F(x) __builtin_amdgcn_exp2f(x)
#else
#define EXP2F(x) __expf(0.6931471805599453f * (x))
#endif

__device__ constexpr float ATc[6][5] = {
    {0.f, 0.f, 0.f, 0.f, 0.f},
    {0.2f, 0.f, 0.f, 0.f, 0.f},
    {3.f/40.f, 9.f/40.f, 0.f, 0.f, 0.f},
    {44.f/45.f, -56.f/15.f, 32.f/9.f, 0.f, 0.f},
    {19372.f/6561.f, -25360.f/2187.f, 64448.f/6561.f, -212.f/729.f, 0.f},
    {9017.f/3168.f, -355.f/33.f, 46732.f/5247.f, 49.f/176.f, -5103.f/18656.f}
};
__device__ constexpr float BTc[6] = {35.f/384.f, 0.f, 500.f/1113.f, 125.f/192.f,
                                     -2187.f/6784.f, 11.f/84.f};

struct Frag2 { bf16x8 h, m; };

__device__ __forceinline__ float tanh_fast(float x) {
    // tanh(x) = 1 - 2/(exp(2x)+1); exp(2x) = exp2(x * 2*log2(e))
    float e = EXP2F(x * 2.8853900817779268f);
    return fmaf(-2.0f, __builtin_amdgcn_rcpf(e + 1.0f), 1.0f);
}

// pack hi16(b):hi16(a) in one v_perm_b32 (bytes 2,3 of a then 2,3 of b)
__device__ __forceinline__ unsigned int permhi(unsigned int b, unsigned int a) {
    return __builtin_amdgcn_perm(b, a, 0x07060302u);
}

// 2-term split: v = h + m + O(2^-17 |v|). h = trunc (residual exact);
// m = round-half-up of residual (+0x8000 carry). Weights only (static).
__device__ __forceinline__ void splitpair(float a, float b,
                                          unsigned int& ph, unsigned int& pm) {
    unsigned int ua = __float_as_uint(a), ub = __float_as_uint(b);
    ph = permhi(ub, ua);
    float ra = a - __uint_as_float(ua & 0xFFFF0000u);
    float rb = b - __uint_as_float(ub & 0xFFFF0000u);
    pm = permhi(__float_as_uint(rb) + 0x8000u, __float_as_uint(ra) + 0x8000u);
}

__device__ __forceinline__ Frag2 split8_2(const float* v) {
    unsigned int wh[4], wm[4];
    #pragma unroll
    for (int p = 0; p < 4; ++p) splitpair(v[2*p], v[2*p+1], wh[p], wm[p]);
    Frag2 f;
    u32x4 H = {wh[0], wh[1], wh[2], wh[3]};
    u32x4 M = {wm[0], wm[1], wm[2], wm[3]};
    f.h = __builtin_bit_cast(bf16x8, H);
    f.m = __builtin_bit_cast(bf16x8, M);
    return f;
}

// round-half-up bf16 pack of two f32 into one u32 (activations: z, yt)
__device__ __forceinline__ unsigned int packpair(float a, float b) {
    return permhi(__float_as_uint(b) + 0x8000u, __float_as_uint(a) + 0x8000u);
}

// z packed to a single bf16 plane (R13-proven)
__device__ __forceinline__ bf16x8 packz(f32x4 a, f32x4 b) {
    u32x4 H = {packpair(a[0], a[1]), packpair(a[2], a[3]),
               packpair(b[0], b[1]), packpair(b[2], b[3])};
    return __builtin_bit_cast(bf16x8, H);
}

// Block = 4 waves = 16 rows, grid 512 (2 blocks/CU) — R6..R13 geometry (proven
// optimum). R14 delta vs R13 (numerics bet #2):
//   yt SINGLE bf16 plane (round-half-up): m1 = (W1h + W1m) . B1h (4 MFMA,
//   was 6), one B1 read (was 2), one yt publish word (was 2). Weight splits
//   unchanged (2-plane). Fallback on fail: R13.
__global__ __launch_bounds__(256, 2)
void NeuralODE_dopri5_r14(const float* __restrict__ x, const float* __restrict__ tptr,
                          const float* __restrict__ W1, const float* __restrict__ b1,
                          const float* __restrict__ W2, const float* __restrict__ b2,
                          float* __restrict__ out)
{
    __shared__ unsigned int ytp[16][16];             // yt plane (single): 1 KB
    __shared__ __align__(16) float pb[4][512];       // m2 partials: 8 KB

    const int tid = threadIdx.x;
    const int w   = tid >> 6;
    const int l   = tid & 63;
    const int r   = l & 15;
    const int q   = l >> 4;
    const int g   = (r >> 1) & 3;                    // plane block swizzle (R6-proven)
    const int swz = (r & 7) << 2;                    // f32-block swizzle (R4-proven)
    const int row = blockIdx.x * 16 + r;
    const int d0  = 8 * w + 2 * q;                   // owned state pair

    // ---- static weight fragments ----
    Frag2 W1f[2];
    f32x4 b1f[2];
    {
        float v[8];
        #pragma unroll
        for (int i = 0; i < 2; ++i) {
            int m = 2 * w + i;
            *(f32x4*)&v[0] = *(const f32x4*)&W1[(16*m + r) * 32 + 8*q];
            *(f32x4*)&v[4] = *(const f32x4*)&W1[(16*m + r) * 32 + 8*q + 4];
            W1f[i] = split8_2(v);
            b1f[i] = *(const f32x4*)&b1[16*m + 4*q];
        }
    }
    // W2 A-fragments with the sigma K-permutation:
    //   A[r][8q+j] = W2[16dt + r][32w + (j<4 ? 4q+j : 16 + 4q + j-4)]
    Frag2 W2f[2];
    {
        float v[8];
        #pragma unroll
        for (int dt = 0; dt < 2; ++dt) {
            *(f32x4*)&v[0] = *(const f32x4*)&W2[(16*dt + r) * 128 + 32*w + 4*q];
            *(f32x4*)&v[4] = *(const f32x4*)&W2[(16*dt + r) * 128 + 32*w + 16 + 4*q];
            W2f[dt] = split8_2(v);
        }
    }
    // b2 folded into wave-0's m2 accumulator init (C-operand); other waves zero.
    const f32x4 zero = {0.f, 0.f, 0.f, 0.f};
    f32x4 acc_init[2];
    #pragma unroll
    for (int dt = 0; dt < 2; ++dt)
        acc_init[dt] = (w == 0) ? *(const f32x4*)&b2[16*dt + 4*q] : zero;

    // ---- loop-invariant LDS addresses ----
    unsigned int* const ytw = &ytp[r][((w ^ g) << 2) + q];
    const u32x4* const ytr  = (const u32x4*)&ytp[r][(q ^ g) << 2];
    float* const pbw0 = &pb[w][r * 32 + ((     4*q) ^ swz)];
    float* const pbw1 = &pb[w][r * 32 + ((16 + 4*q) ^ swz)];
    const float* const pred = &pb[0][r * 32 + (d0 ^ swz)];   // + 512*v

    const float h_all = tptr[l + 1] - tptr[l];   // t row 0 uniform; lane s has h_s

    // ---- state init ----
    float2 y0 = *(const float2*)&x[(size_t)row * (TT*32) + d0];
    float yx = y0.x, yy = y0.y;
    *ytw = packpair(yx, yy);
    *(float2*)&out[(size_t)row * (TT*32) + d0] = y0;
    float kxs[5], kys[5];
    __syncthreads();

    #pragma unroll 1
    for (int step = 0; step < NSTEP; ++step) {
        const float h = __shfl(h_all, step);
        float bax = 0.f, bay = 0.f;

        #pragma unroll
        for (int s = 0; s < 6; ++s) {
            // ---- B1 fragment: single plane, direct from LDS ----
            bf16x8 B1 = __builtin_bit_cast(bf16x8, *ytr);

            // ---- m1: 2 tiles x 2 products (W1 2-plane x B1 1-plane) + tanh ----
            f32x4 z0 = b1f[0];
            z0 = MFMA32(W1f[0].h, B1, z0);
            z0 = MFMA32(W1f[0].m, B1, z0);
            f32x4 z1 = b1f[1];
            z1 = MFMA32(W1f[1].h, B1, z1);
            z1 = MFMA32(W1f[1].m, B1, z1);
            #pragma unroll
            for (int e = 0; e < 4; ++e) { z0[e] = tanh_fast(z0[e]); z1[e] = tanh_fast(z1[e]); }

            // ---- z -> single-plane MFMA32 B-fragment (sigma concat) ----
            bf16x8 Zh = packz(z0, z1);

            // ---- m2: 2 d-tiles x 2 products, K=32 ----
            f32x4 p0 = acc_init[0];
            p0 = MFMA32(W2f[0].h, Zh, p0);
            p0 = MFMA32(W2f[0].m, Zh, p0);
            f32x4 p1 = acc_init[1];
            p1 = MFMA32(W2f[1].h, Zh, p1);
            p1 = MFMA32(W2f[1].m, Zh, p1);
            *(f32x4*)pbw0 = p0;
            *(f32x4*)pbw1 = p1;
            __syncthreads();

            // ---- owner: reduce 4 partials (b2 already in), update, publish ----
            float2 pp0 = *(const float2*)&pred[0 * 512];
            float2 pp1 = *(const float2*)&pred[1 * 512];
            float2 pp2 = *(const float2*)&pred[2 * 512];
            float2 pp3 = *(const float2*)&pred[3 * 512];
            float kx = (pp0.x + pp1.x) + (pp2.x + pp3.x);
            float ky = (pp0.y + pp1.y) + (pp2.y + pp3.y);
            if (s < 5) { kxs[s] = kx; kys[s] = ky; }
            bax = fmaf(BTc[s], kx, bax);
            bay = fmaf(BTc[s], ky, bay);

            float ytx, yty;
            if (s < 5) {
                float ax = ATc[s+1][s] * kx;
                float ay = ATc[s+1][s] * ky;
                #pragma unroll
                for (int j = 0; j < 5; ++j)
                    if (j < s) { ax = fmaf(ATc[s+1][j], kxs[j], ax);
                                 ay = fmaf(ATc[s+1][j], kys[j], ay); }
                ytx = fmaf(h, ax, yx);
                yty = fmaf(h, ay, yy);
            } else {
                yx = fmaf(h, bax, yx);
                yy = fmaf(h, bay, yy);
                ytx = yx; yty = yy;
                float2 yn = {yx, yy};
                *(float2*)&out[(size_t)row * (TT*32) + (size_t)(step+1) * 32 + d0] = yn;
            }
            *ytw = packpair(ytx, yty);
            __syncthreads();
        }
    }
}

extern "C" void kernel_launch(void* const* d_in, const int* in_sizes, int n_in,
                              void* d_out, int out_size, void* d_ws, size_t ws_size,
                              hipStream_t stream) {
    (void)in_sizes; (void)n_in; (void)d_ws; (void)ws_size; (void)out_size;
    const float* x  = (const float*)d_in[0];
    const float* t  = (const float*)d_in[1];
    // d_in[2] = itv, d_in[3] = itv_mask : unused by the reference math
    const float* W1 = (const float*)d_in[4];
    const float* b1 = (const float*)d_in[5];
    const float* W2 = (const float*)d_in[6];
    const float* b2 = (const float*)d_in[7];
    float* out = (float*)d_out;

    dim3 grid(8192 / 16);   // 512 blocks x 4 waves (2 blocks/CU, R6 geometry)
    dim3 block(256);
    hipLaunchKernelGGL(NeuralODE_dopri5_r14, grid, block, 0, stream,
                       x, t, W1, b1, W2, b2, out);
}

// Round 15
// 230.041 us; speedup vs baseline: 2.9415x; 1.0227x over previous
//
#include <hip/hip_runtime.h>

#define TT 65
#define NSTEP 64

typedef __attribute__((ext_vector_type(8))) short bf16x8;
typedef __attribute__((ext_vector_type(4))) float f32x4;
typedef __attribute__((ext_vector_type(4))) unsigned int u32x4;

#define MFMA32(A,B,C) __builtin_amdgcn_mfma_f32_16x16x32_bf16((A),(B),(C),0,0,0)

// native exp2 (single trans op); fallback keeps correctness if builtin absent
#if __has_builtin(__builtin_amdgcn_exp2f)
#define EXP2F(x) __builtin_amdgcn_exp2f(x)
#else
#define EXP2F(x) __expf(0.6931471805599453f * (x))
#endif

__device__ constexpr float ATc[6][5] = {
    {0.f, 0.f, 0.f, 0.f, 0.f},
    {0.2f, 0.f, 0.f, 0.f, 0.f},
    {3.f/40.f, 9.f/40.f, 0.f, 0.f, 0.f},
    {44.f/45.f, -56.f/15.f, 32.f/9.f, 0.f, 0.f},
    {19372.f/6561.f, -25360.f/2187.f, 64448.f/6561.f, -212.f/729.f, 0.f},
    {9017.f/3168.f, -355.f/33.f, 46732.f/5247.f, 49.f/176.f, -5103.f/18656.f}
};
__device__ constexpr float BTc[6] = {35.f/384.f, 0.f, 500.f/1113.f, 125.f/192.f,
                                     -2187.f/6784.f, 11.f/84.f};

__device__ __forceinline__ float tanh_fast(float x) {
    // tanh(x) = 1 - 2/(exp(2x)+1); exp(2x) = exp2(x * 2*log2(e))
    float e = EXP2F(x * 2.8853900817779268f);
    return fmaf(-2.0f, __builtin_amdgcn_rcpf(e + 1.0f), 1.0f);
}

// pack hi16(b):hi16(a) in one v_perm_b32 (bytes 2,3 of a then 2,3 of b)
__device__ __forceinline__ unsigned int permhi(unsigned int b, unsigned int a) {
    return __builtin_amdgcn_perm(b, a, 0x07060302u);
}

// round-half-up bf16 pack of two f32 into one u32
__device__ __forceinline__ unsigned int packpair(float a, float b) {
    return permhi(__float_as_uint(b) + 0x8000u, __float_as_uint(a) + 0x8000u);
}

// round-half-up bf16 pack of 8 f32 (R15: weights are single-plane bf16)
__device__ __forceinline__ bf16x8 pack8(const float* v) {
    u32x4 H = {packpair(v[0], v[1]), packpair(v[2], v[3]),
               packpair(v[4], v[5]), packpair(v[6], v[7])};
    return __builtin_bit_cast(bf16x8, H);
}

// z packed to a single bf16 plane (R13-proven)
__device__ __forceinline__ bf16x8 packz(f32x4 a, f32x4 b) {
    u32x4 H = {packpair(a[0], a[1]), packpair(a[2], a[3]),
               packpair(b[0], b[1]), packpair(b[2], b[3])};
    return __builtin_bit_cast(bf16x8, H);
}

// Block = 4 waves = 16 rows, grid 512 (2 blocks/CU) — R6..R14 geometry (proven
// optimum). R15 delta vs R14 (numerics bet #3, chain-shortening):
//   SINGLE-plane bf16 weights (drop W1m, W2m): m1 = 1 MFMA per c-tile,
//   m2 = 1 MFMA per d-tile (4 MFMA/wave-stage total, single-MFMA chains).
//   Error adds ~2.3e-3 per k (same order as R13's accepted z-bet).
//   Fallback on fail: R14 (banked at 235.3 us).
__global__ __launch_bounds__(256, 2)
void NeuralODE_dopri5_r15(const float* __restrict__ x, const float* __restrict__ tptr,
                          const float* __restrict__ W1, const float* __restrict__ b1,
                          const float* __restrict__ W2, const float* __restrict__ b2,
                          float* __restrict__ out)
{
    __shared__ unsigned int ytp[16][16];             // yt plane (single): 1 KB
    __shared__ __align__(16) float pb[4][512];       // m2 partials: 8 KB

    const int tid = threadIdx.x;
    const int w   = tid >> 6;
    const int l   = tid & 63;
    const int r   = l & 15;
    const int q   = l >> 4;
    const int g   = (r >> 1) & 3;                    // plane block swizzle (R6-proven)
    const int swz = (r & 7) << 2;                    // f32-block swizzle (R4-proven)
    const int row = blockIdx.x * 16 + r;
    const int d0  = 8 * w + 2 * q;                   // owned state pair

    // ---- static weight fragments (single-plane bf16) ----
    bf16x8 W1f[2];
    f32x4 b1f[2];
    {
        float v[8];
        #pragma unroll
        for (int i = 0; i < 2; ++i) {
            int m = 2 * w + i;
            *(f32x4*)&v[0] = *(const f32x4*)&W1[(16*m + r) * 32 + 8*q];
            *(f32x4*)&v[4] = *(const f32x4*)&W1[(16*m + r) * 32 + 8*q + 4];
            W1f[i] = pack8(v);
            b1f[i] = *(const f32x4*)&b1[16*m + 4*q];
        }
    }
    // W2 A-fragments with the sigma K-permutation:
    //   A[r][8q+j] = W2[16dt + r][32w + (j<4 ? 4q+j : 16 + 4q + j-4)]
    bf16x8 W2f[2];
    {
        float v[8];
        #pragma unroll
        for (int dt = 0; dt < 2; ++dt) {
            *(f32x4*)&v[0] = *(const f32x4*)&W2[(16*dt + r) * 128 + 32*w + 4*q];
            *(f32x4*)&v[4] = *(const f32x4*)&W2[(16*dt + r) * 128 + 32*w + 16 + 4*q];
            W2f[dt] = pack8(v);
        }
    }
    // b2 folded into wave-0's m2 accumulator init (C-operand); other waves zero.
    const f32x4 zero = {0.f, 0.f, 0.f, 0.f};
    f32x4 acc_init[2];
    #pragma unroll
    for (int dt = 0; dt < 2; ++dt)
        acc_init[dt] = (w == 0) ? *(const f32x4*)&b2[16*dt + 4*q] : zero;

    // ---- loop-invariant LDS addresses ----
    unsigned int* const ytw = &ytp[r][((w ^ g) << 2) + q];
    const u32x4* const ytr  = (const u32x4*)&ytp[r][(q ^ g) << 2];
    float* const pbw0 = &pb[w][r * 32 + ((     4*q) ^ swz)];
    float* const pbw1 = &pb[w][r * 32 + ((16 + 4*q) ^ swz)];
    const float* const pred = &pb[0][r * 32 + (d0 ^ swz)];   // + 512*v

    const float h_all = tptr[l + 1] - tptr[l];   // t row 0 uniform; lane s has h_s

    // ---- state init ----
    float2 y0 = *(const float2*)&x[(size_t)row * (TT*32) + d0];
    float yx = y0.x, yy = y0.y;
    *ytw = packpair(yx, yy);
    *(float2*)&out[(size_t)row * (TT*32) + d0] = y0;
    float kxs[5], kys[5];
    __syncthreads();

    #pragma unroll 1
    for (int step = 0; step < NSTEP; ++step) {
        const float h = __shfl(h_all, step);
        float bax = 0.f, bay = 0.f;

        #pragma unroll
        for (int s = 0; s < 6; ++s) {
            // ---- B1 fragment: single plane, direct from LDS ----
            bf16x8 B1 = __builtin_bit_cast(bf16x8, *ytr);

            // ---- m1: 2 tiles x 1 MFMA + tanh ----
            f32x4 z0 = MFMA32(W1f[0], B1, b1f[0]);
            f32x4 z1 = MFMA32(W1f[1], B1, b1f[1]);
            #pragma unroll
            for (int e = 0; e < 4; ++e) { z0[e] = tanh_fast(z0[e]); z1[e] = tanh_fast(z1[e]); }

            // ---- z -> single-plane MFMA32 B-fragment (sigma concat) ----
            bf16x8 Zh = packz(z0, z1);

            // ---- m2: 2 d-tiles x 1 MFMA, K=32 ----
            f32x4 p0 = MFMA32(W2f[0], Zh, acc_init[0]);
            f32x4 p1 = MFMA32(W2f[1], Zh, acc_init[1]);
            *(f32x4*)pbw0 = p0;
            *(f32x4*)pbw1 = p1;
            __syncthreads();

            // ---- owner: reduce 4 partials (b2 already in), update, publish ----
            float2 pp0 = *(const float2*)&pred[0 * 512];
            float2 pp1 = *(const float2*)&pred[1 * 512];
            float2 pp2 = *(const float2*)&pred[2 * 512];
            float2 pp3 = *(const float2*)&pred[3 * 512];
            float kx = (pp0.x + pp1.x) + (pp2.x + pp3.x);
            float ky = (pp0.y + pp1.y) + (pp2.y + pp3.y);
            if (s < 5) { kxs[s] = kx; kys[s] = ky; }
            bax = fmaf(BTc[s], kx, bax);
            bay = fmaf(BTc[s], ky, bay);

            float ytx, yty;
            if (s < 5) {
                float ax = ATc[s+1][s] * kx;
                float ay = ATc[s+1][s] * ky;
                #pragma unroll
                for (int j = 0; j < 5; ++j)
                    if (j < s) { ax = fmaf(ATc[s+1][j], kxs[j], ax);
                                 ay = fmaf(ATc[s+1][j], kys[j], ay); }
                ytx = fmaf(h, ax, yx);
                yty = fmaf(h, ay, yy);
            } else {
                yx = fmaf(h, bax, yx);
                yy = fmaf(h, bay, yy);
                ytx = yx; yty = yy;
                float2 yn = {yx, yy};
                *(float2*)&out[(size_t)row * (TT*32) + (size_t)(step+1) * 32 + d0] = yn;
            }
            *ytw = packpair(ytx, yty);
            __syncthreads();
        }
    }
}

extern "C" void kernel_launch(void* const* d_in, const int* in_sizes, int n_in,
                              void* d_out, int out_size, void* d_ws, size_t ws_size,
                              hipStream_t stream) {
    (void)in_sizes; (void)n_in; (void)d_ws; (void)ws_size; (void)out_size;
    const float* x  = (const float*)d_in[0];
    const float* t  = (const float*)d_in[1];
    // d_in[2] = itv, d_in[3] = itv_mask : unused by the reference math
    const float* W1 = (const float*)d_in[4];
    const float* b1 = (const float*)d_in[5];
    const float* W2 = (const float*)d_in[6];
    const float* b2 = (const float*)d_in[7];
    float* out = (float*)d_out;

    dim3 grid(8192 / 16);   // 512 blocks x 4 waves (2 blocks/CU, R6 geometry)
    dim3 block(256);
    hipLaunchKernelGGL(NeuralODE_dopri5_r15, grid, block, 0, stream,
                       x, t, W1, b1, W2, b2, out);
}

// Round 16
// 220.105 us; speedup vs baseline: 3.0743x; 1.0451x over previous
//
#include <hip/hip_runtime.h>

#define TT 65
#define NSTEP 64

typedef __attribute__((ext_vector_type(8))) short bf16x8;
typedef __attribute__((ext_vector_type(4))) float f32x4;
typedef __attribute__((ext_vector_type(4))) unsigned int u32x4;

#define MFMA32(A,B,C) __builtin_amdgcn_mfma_f32_16x16x32_bf16((A),(B),(C),0,0,0)

// native exp2 (single trans op); fallback keeps correctness if builtin absent
#if __has_builtin(__builtin_amdgcn_exp2f)
#define EXP2F(x) __builtin_amdgcn_exp2f(x)
#else
#define EXP2F(x) __expf(0.6931471805599453f * (x))
#endif

__device__ constexpr float ATc[6][5] = {
    {0.f, 0.f, 0.f, 0.f, 0.f},
    {0.2f, 0.f, 0.f, 0.f, 0.f},
    {3.f/40.f, 9.f/40.f, 0.f, 0.f, 0.f},
    {44.f/45.f, -56.f/15.f, 32.f/9.f, 0.f, 0.f},
    {19372.f/6561.f, -25360.f/2187.f, 64448.f/6561.f, -212.f/729.f, 0.f},
    {9017.f/3168.f, -355.f/33.f, 46732.f/5247.f, 49.f/176.f, -5103.f/18656.f}
};
__device__ constexpr float BTc[6] = {35.f/384.f, 0.f, 500.f/1113.f, 125.f/192.f,
                                     -2187.f/6784.f, 11.f/84.f};

__device__ __forceinline__ float tanh_fast(float x) {
    // tanh(x) = 1 - 2/(exp(2x)+1); exp(2x) = exp2(x * 2*log2(e))
    float e = EXP2F(x * 2.8853900817779268f);
    return fmaf(-2.0f, __builtin_amdgcn_rcpf(e + 1.0f), 1.0f);
}

// R16: barrier-lite. __syncthreads drains vmcnt(0) too — stalling each
// post-store barrier ~hundreds of cycles on an HBM store nothing reads.
// LDS producer->consumer only needs lgkmcnt(0) + s_barrier.
__device__ __forceinline__ void barrier_lds() {
    asm volatile("s_waitcnt lgkmcnt(0)" ::: "memory");
    __builtin_amdgcn_s_barrier();
}

// pack hi16(b):hi16(a) in one v_perm_b32 (weights init only)
__device__ __forceinline__ unsigned int permhi(unsigned int b, unsigned int a) {
    return __builtin_amdgcn_perm(b, a, 0x07060302u);
}
__device__ __forceinline__ unsigned int packpair_init(float a, float b) {
    return permhi(__float_as_uint(b) + 0x8000u, __float_as_uint(a) + 0x8000u);
}
__device__ __forceinline__ bf16x8 pack8(const float* v) {
    u32x4 H = {packpair_init(v[0], v[1]), packpair_init(v[2], v[3]),
               packpair_init(v[4], v[5]), packpair_init(v[6], v[7])};
    return __builtin_bit_cast(bf16x8, H);
}

// R16: hot-path pack via HW v_cvt_pk_bf16_f32 (1 VOP3 per pair, RNE) — T12
__device__ __forceinline__ unsigned int cvtpk(float a, float b) {
    unsigned int r;
    asm("v_cvt_pk_bf16_f32 %0, %1, %2" : "=v"(r) : "v"(a), "v"(b));
    return r;
}
__device__ __forceinline__ bf16x8 packz(f32x4 a, f32x4 b) {
    u32x4 H = {cvtpk(a[0], a[1]), cvtpk(a[2], a[3]),
               cvtpk(b[0], b[1]), cvtpk(b[2], b[3])};
    return __builtin_bit_cast(bf16x8, H);
}

// Block = 4 waves = 16 rows, grid 512 (2 blocks/CU) — R6..R15 geometry (proven
// optimum). R16 deltas vs R15 (stall-cut only, work & numerics ~unchanged):
//   barrier-lite (lgkmcnt-only barriers; out-store never drained in-loop),
//   v_cvt_pk_bf16_f32 activation packing (5 ops vs 15 per stage).
__global__ __launch_bounds__(256, 2)
void NeuralODE_dopri5_r16(const float* __restrict__ x, const float* __restrict__ tptr,
                          const float* __restrict__ W1, const float* __restrict__ b1,
                          const float* __restrict__ W2, const float* __restrict__ b2,
                          float* __restrict__ out)
{
    __shared__ unsigned int ytp[16][16];             // yt plane (single): 1 KB
    __shared__ __align__(16) float pb[4][512];       // m2 partials: 8 KB

    const int tid = threadIdx.x;
    const int w   = tid >> 6;
    const int l   = tid & 63;
    const int r   = l & 15;
    const int q   = l >> 4;
    const int g   = (r >> 1) & 3;                    // plane block swizzle (R6-proven)
    const int swz = (r & 7) << 2;                    // f32-block swizzle (R4-proven)
    const int row = blockIdx.x * 16 + r;
    const int d0  = 8 * w + 2 * q;                   // owned state pair

    // ---- static weight fragments (single-plane bf16) ----
    bf16x8 W1f[2];
    f32x4 b1f[2];
    {
        float v[8];
        #pragma unroll
        for (int i = 0; i < 2; ++i) {
            int m = 2 * w + i;
            *(f32x4*)&v[0] = *(const f32x4*)&W1[(16*m + r) * 32 + 8*q];
            *(f32x4*)&v[4] = *(const f32x4*)&W1[(16*m + r) * 32 + 8*q + 4];
            W1f[i] = pack8(v);
            b1f[i] = *(const f32x4*)&b1[16*m + 4*q];
        }
    }
    // W2 A-fragments with the sigma K-permutation:
    //   A[r][8q+j] = W2[16dt + r][32w + (j<4 ? 4q+j : 16 + 4q + j-4)]
    bf16x8 W2f[2];
    {
        float v[8];
        #pragma unroll
        for (int dt = 0; dt < 2; ++dt) {
            *(f32x4*)&v[0] = *(const f32x4*)&W2[(16*dt + r) * 128 + 32*w + 4*q];
            *(f32x4*)&v[4] = *(const f32x4*)&W2[(16*dt + r) * 128 + 32*w + 16 + 4*q];
            W2f[dt] = pack8(v);
        }
    }
    // b2 folded into wave-0's m2 accumulator init (C-operand); other waves zero.
    const f32x4 zero = {0.f, 0.f, 0.f, 0.f};
    f32x4 acc_init[2];
    #pragma unroll
    for (int dt = 0; dt < 2; ++dt)
        acc_init[dt] = (w == 0) ? *(const f32x4*)&b2[16*dt + 4*q] : zero;

    // ---- loop-invariant LDS addresses ----
    unsigned int* const ytw = &ytp[r][((w ^ g) << 2) + q];
    const u32x4* const ytr  = (const u32x4*)&ytp[r][(q ^ g) << 2];
    float* const pbw0 = &pb[w][r * 32 + ((     4*q) ^ swz)];
    float* const pbw1 = &pb[w][r * 32 + ((16 + 4*q) ^ swz)];
    const float* const pred = &pb[0][r * 32 + (d0 ^ swz)];   // + 512*v

    const float h_all = tptr[l + 1] - tptr[l];   // t row 0 uniform; lane s has h_s

    // ---- state init ----
    float2 y0 = *(const float2*)&x[(size_t)row * (TT*32) + d0];
    float yx = y0.x, yy = y0.y;
    *ytw = cvtpk(yx, yy);
    *(float2*)&out[(size_t)row * (TT*32) + d0] = y0;
    float kxs[5], kys[5];
    barrier_lds();

    #pragma unroll 1
    for (int step = 0; step < NSTEP; ++step) {
        const float h = __shfl(h_all, step);
        float bax = 0.f, bay = 0.f;

        #pragma unroll
        for (int s = 0; s < 6; ++s) {
            // ---- B1 fragment: single plane, direct from LDS ----
            bf16x8 B1 = __builtin_bit_cast(bf16x8, *ytr);

            // ---- m1: 2 tiles x 1 MFMA + tanh ----
            f32x4 z0 = MFMA32(W1f[0], B1, b1f[0]);
            f32x4 z1 = MFMA32(W1f[1], B1, b1f[1]);
            #pragma unroll
            for (int e = 0; e < 4; ++e) { z0[e] = tanh_fast(z0[e]); z1[e] = tanh_fast(z1[e]); }

            // ---- z -> single-plane MFMA32 B-fragment (sigma concat) ----
            bf16x8 Zh = packz(z0, z1);

            // ---- m2: 2 d-tiles x 1 MFMA, K=32 ----
            f32x4 p0 = MFMA32(W2f[0], Zh, acc_init[0]);
            f32x4 p1 = MFMA32(W2f[1], Zh, acc_init[1]);
            *(f32x4*)pbw0 = p0;
            *(f32x4*)pbw1 = p1;
            barrier_lds();

            // ---- owner: reduce 4 partials (b2 already in), update, publish ----
            float2 pp0 = *(const float2*)&pred[0 * 512];
            float2 pp1 = *(const float2*)&pred[1 * 512];
            float2 pp2 = *(const float2*)&pred[2 * 512];
            float2 pp3 = *(const float2*)&pred[3 * 512];
            float kx = (pp0.x + pp1.x) + (pp2.x + pp3.x);
            float ky = (pp0.y + pp1.y) + (pp2.y + pp3.y);
            if (s < 5) { kxs[s] = kx; kys[s] = ky; }
            bax = fmaf(BTc[s], kx, bax);
            bay = fmaf(BTc[s], ky, bay);

            float ytx, yty;
            if (s < 5) {
                float ax = ATc[s+1][s] * kx;
                float ay = ATc[s+1][s] * ky;
                #pragma unroll
                for (int j = 0; j < 5; ++j)
                    if (j < s) { ax = fmaf(ATc[s+1][j], kxs[j], ax);
                                 ay = fmaf(ATc[s+1][j], kys[j], ay); }
                ytx = fmaf(h, ax, yx);
                yty = fmaf(h, ay, yy);
            } else {
                yx = fmaf(h, bax, yx);
                yy = fmaf(h, bay, yy);
                ytx = yx; yty = yy;
                float2 yn = {yx, yy};
                *(float2*)&out[(size_t)row * (TT*32) + (size_t)(step+1) * 32 + d0] = yn;
            }
            *ytw = cvtpk(ytx, yty);
            barrier_lds();
        }
    }
}

extern "C" void kernel_launch(void* const* d_in, const int* in_sizes, int n_in,
                              void* d_out, int out_size, void* d_ws, size_t ws_size,
                              hipStream_t stream) {
    (void)in_sizes; (void)n_in; (void)d_ws; (void)ws_size; (void)out_size;
    const float* x  = (const float*)d_in[0];
    const float* t  = (const float*)d_in[1];
    // d_in[2] = itv, d_in[3] = itv_mask : unused by the reference math
    const float* W1 = (const float*)d_in[4];
    const float* b1 = (const float*)d_in[5];
    const float* W2 = (const float*)d_in[6];
    const float* b2 = (const float*)d_in[7];
    float* out = (float*)d_out;

    dim3 grid(8192 / 16);   // 512 blocks x 4 waves (2 blocks/CU, R6 geometry)
    dim3 block(256);
    hipLaunchKernelGGL(NeuralODE_dopri5_r16, grid, block, 0, stream,
                       x, t, W1, b1, W2, b2, out);
}